// Round 1
// baseline (359.467 us; speedup 1.0000x reference)
//
#include <hip/hip_runtime.h>
#include <math.h>

// ---- problem constants ----
#define N_NODES 33
#define SEQ 24
#define BATCH 64
#define G_GRAPHS (BATCH * SEQ)          // 1536
#define EPG 64
#define E_EDGES (G_GRAPHS * EPG)        // 98304
#define N_TOTAL (G_GRAPHS * N_NODES)    // 50688
#define HID 64
#define HEADS 8
#define HC (HID * HEADS)                // 512
#define LSTM1_H 128
#define LSTM2_H 64
#define NEG_SLOPE 0.2f
// conv fused into gat1 chunk 0: 128 transpose tiles + 264 W1f blocks
#define CONV_BLOCKS (128 + 264)

__device__ __forceinline__ float sigmoidf_(float x) { return 1.f / (1.f + expf(-x)); }
__device__ __forceinline__ float eluf_(float x) { return x > 0.f ? x : expm1f(x); }
__device__ __forceinline__ float lreluf_(float x) { return x > 0.f ? x : NEG_SLOPE * x; }

typedef __attribute__((ext_vector_type(4))) float f32x4;
typedef _Float16 half_t;
typedef __attribute__((ext_vector_type(8))) _Float16 halfx8;

__device__ __forceinline__ void gl2lds16(const void* g, void* l) {
  __builtin_amdgcn_global_load_lds(
      (__attribute__((address_space(1))) const unsigned int*)g,
      (__attribute__((address_space(3))) unsigned int*)l, 16, 0, 0);
}

// ============================================================
// GAT layer 1, 512 threads (8 waves). Blocks >= gat_blocks do the one-time
// fp16 weight conversion: 128 LDS-transpose tiles + 264 elementwise W1f blocks.
// ============================================================
__global__ __launch_bounds__(512) void gat1_kernel(
    const float* __restrict__ x, const int* __restrict__ src, const int* __restrict__ dst,
    const float* __restrict__ ea, const float* __restrict__ Wl, const float* __restrict__ Wr,
    const float* __restrict__ We, const float* __restrict__ att, const float* __restrict__ bias,
    half_t* __restrict__ h1, int g0, int gat_blocks,
    const float* __restrict__ g2Wl, const float* __restrict__ g2Wr,
    half_t* __restrict__ B2, const float* __restrict__ W1, half_t* __restrict__ W1f) {
  const int tid = threadIdx.x;

  __shared__ alignas(16) float Wl_s[2 * 512];
  __shared__ alignas(16) float Wr_s[2 * 512];
  __shared__ alignas(16) float We_s[3 * 512];
  __shared__ alignas(16) float att_s[512];
  __shared__ float xs0_s[N_NODES + 1], xs1_s[N_NODES + 1];
  __shared__ float easX[EPG], easY[EPG], easZ[EPG];
  __shared__ float logit_s[HEADS * 65];
  __shared__ int sloc[EPG], dloc[EPG], deg[N_NODES], start[N_NODES], fill[N_NODES], elist[EPG];
  __shared__ float tr[64 * 65];          // transpose tile (conv path)

  if ((int)blockIdx.x >= gat_blocks) {
    int cb = blockIdx.x - gat_blocks;
    if (cb < 128) {
      // transpose B2[n][k] = [Wl|Wr][k][n], 64x64 tile, coalesced both ways
      int kt = cb & 7, nt = cb >> 3;
      int k0 = kt * 64, n0 = nt * 64;
      int r = tid >> 6, c = tid & 63;
      #pragma unroll
      for (int rr = 0; rr < 8; ++rr) {
        int kl = rr * 8 + r;
        int n = n0 + c;
        float v = (n < 512) ? g2Wl[(size_t)(k0 + kl) * 512 + n]
                            : g2Wr[(size_t)(k0 + kl) * 512 + n - 512];
        tr[kl * 65 + c] = v;
      }
      __syncthreads();
      #pragma unroll
      for (int rr = 0; rr < 8; ++rr) {
        int nl = rr * 8 + r;
        B2[(size_t)(n0 + nl) * 512 + k0 + c] = (half_t)tr[c * 65 + nl];
      }
    } else {
      int base = (cb - 128) * 4096 + tid;
      #pragma unroll
      for (int i = 0; i < 8; ++i) {
        int idx = base + i * 512;
        if (idx < 512 * 2112) W1f[idx] = (half_t)W1[idx];
      }
    }
    return;
  }

  const int g = g0 + blockIdx.x;
  const int nb = g * N_NODES, eb = g * EPG;
  const int lb = blockIdx.x * N_NODES;

  for (int i = tid; i < 1024; i += 512) { Wl_s[i] = Wl[i]; Wr_s[i] = Wr[i]; }
  for (int i = tid; i < 1536; i += 512) We_s[i] = We[i];
  if (tid < 512) att_s[tid] = att[tid];
  if (tid < 2 * N_NODES) {
    float v = x[nb * 2 + tid];
    if (tid & 1) xs1_s[tid >> 1] = v; else xs0_s[tid >> 1] = v;
  }
  if (tid < EPG) {
    easX[tid] = ea[(eb + tid) * 3 + 0];
    easY[tid] = ea[(eb + tid) * 3 + 1];
    easZ[tid] = ea[(eb + tid) * 3 + 2];
    sloc[tid] = src[eb + tid] - nb;
    dloc[tid] = dst[eb + tid] - nb;
  }
  if (tid < N_NODES) { deg[tid] = 0; fill[tid] = 0; }
  __syncthreads();
  if (tid < EPG) atomicAdd(&deg[dloc[tid]], 1);
  __syncthreads();
  if (tid == 0) { int a = 0; for (int n = 0; n < N_NODES; ++n) { start[n] = a; a += deg[n]; } }
  __syncthreads();
  if (tid < EPG) { int d = dloc[tid]; int p = atomicAdd(&fill[d], 1); elist[start[d] + p] = tid; }

  // logits: one pass, h = tid>>6 (wave-uniform), e = lane
  {
    int h = tid >> 6, e = tid & 63;
    int s = sloc[e], d = dloc[e];
    float xs0 = xs0_s[s], xs1 = xs1_s[s], xd0 = xs0_s[d], xd1 = xs1_s[d];
    float e0 = easX[e], e1 = easY[e], e2 = easZ[e];
    float acc = 0.f;
    int base = h * 64;
    #pragma unroll
    for (int c4 = 0; c4 < 16; ++c4) {
      int j = base + c4 * 4;
      f32x4 wl0 = *(const f32x4*)(Wl_s + j);
      f32x4 wl1 = *(const f32x4*)(Wl_s + 512 + j);
      f32x4 wr0 = *(const f32x4*)(Wr_s + j);
      f32x4 wr1 = *(const f32x4*)(Wr_s + 512 + j);
      f32x4 we0 = *(const f32x4*)(We_s + j);
      f32x4 we1 = *(const f32x4*)(We_s + 512 + j);
      f32x4 we2 = *(const f32x4*)(We_s + 1024 + j);
      f32x4 at  = *(const f32x4*)(att_s + j);
      #pragma unroll
      for (int q = 0; q < 4; ++q) {
        float v = xs0 * wl0[q] + xs1 * wl1[q]
                + xd0 * wr0[q] + xd1 * wr1[q]
                + e0 * we0[q] + e1 * we1[q] + e2 * we2[q];
        acc += lreluf_(v) * at[q];
      }
    }
    logit_s[h * 65 + e] = acc;
  }
  __syncthreads();

  // segment softmax: one pass, h = tid>>6, n = lane (skip n>=33)
  {
    int h = tid >> 6, n = tid & 63;
    if (n < N_NODES) {
      int s0 = start[n], dn = deg[n];
      float mx = -1e30f;
      for (int i = 0; i < dn; ++i) mx = fmaxf(mx, logit_s[h * 65 + elist[s0 + i]]);
      float den = 0.f;
      for (int i = 0; i < dn; ++i) den += expf(logit_s[h * 65 + elist[s0 + i]] - mx);
      float inv = 1.f / (den + 1e-16f);
      for (int i = 0; i < dn; ++i) {
        int e = elist[s0 + i];
        logit_s[h * 65 + e] = expf(logit_s[h * 65 + e] - mx) * inv;
      }
    }
  }
  __syncthreads();

  // aggregation: task = (n, 8-channel block); n = t>>6 wave-uniform, jb = lane
  for (int t = tid; t < N_NODES * 64; t += 512) {
    int n = t >> 6, jb = t & 63;
    int j0 = jb * 8, h = jb >> 3;
    f32x4 wa0 = *(const f32x4*)(Wl_s + j0);
    f32x4 wa1 = *(const f32x4*)(Wl_s + j0 + 4);
    f32x4 wb0 = *(const f32x4*)(Wl_s + 512 + j0);
    f32x4 wb1 = *(const f32x4*)(Wl_s + 512 + j0 + 4);
    float acc[8] = {};
    int s0 = start[n], dn = deg[n];
    for (int i = 0; i < dn; ++i) {
      int e = elist[s0 + i]; int s = sloc[e];
      float a = logit_s[h * 65 + e];
      float ax0 = a * xs0_s[s], ax1 = a * xs1_s[s];
      #pragma unroll
      for (int q = 0; q < 4; ++q) {
        acc[q]     += ax0 * wa0[q] + ax1 * wb0[q];
        acc[4 + q] += ax0 * wa1[q] + ax1 * wb1[q];
      }
    }
    f32x4 b0 = *(const f32x4*)(bias + j0);
    f32x4 b1 = *(const f32x4*)(bias + j0 + 4);
    halfx8 vh;
    #pragma unroll
    for (int cc = 0; cc < 8; ++cc) {
      float bb = (cc < 4) ? b0[cc] : b1[cc - 4];
      vh[cc] = (half_t)eluf_(acc[cc] + bb);
    }
    *(halfx8*)(h1 + (size_t)(lb + n) * HC + j0) = vh;
  }
}

// ============================================================
// Main GEMM rewritten (round-16): 256x256 tile, 512 threads (8 waves, 2Mx4N),
// 4-slot LDS ring of BK=32 panels (128 KiB), staging issued 3 K-tiles ahead.
// Sync per K-tile: counted s_waitcnt vmcnt(8) (never 0 in the main loop) +
// ONE raw s_barrier. Staging for tile t+3 is issued only after the barrier
// of tile t, when the ring slot's previous readers (tile t-1) are provably
// done. Correctness chain: wave V's vmcnt(8) at tile t drains V's tile-t
// loads; the barrier publishes that to all waves before any tile-t ds_read.
// T5: s_setprio(1) around the 32-MFMA cluster.
// A: M x 512 f16 (row-major, stride 512). B: 1024 x 512 f16 (row = out ch).
// C: M x 1024 f16. M must be divisible by 256.
// ============================================================
__global__ __launch_bounds__(512, 2) void gemm256(
    const half_t* __restrict__ A, const half_t* __restrict__ B,
    half_t* __restrict__ C, int M) {
  __shared__ alignas(16) half_t lds[65536];   // 128 KiB: 4 slots x (A 256x32 + B 256x32)

  const int R = M >> 8;                 // row tiles
  int b = blockIdx.x;
  int xcd = b & 7, q = b >> 3;
  int ct = q & 3, rg = q >> 2;          // NT = 1024/256 = 4 col tiles
  int r = rg * 8 + xcd;
  if (r >= R) return;

  const int tid = threadIdx.x;
  const int wave = tid >> 6, lane = tid & 63;
  const int wm = wave >> 2, wn = wave & 3;       // 2M x 4N wave grid
  const int bm = r << 8, bn = ct << 8;

  // staging swizzle (pre-swizzled global source, linear LDS dest)
  const int rA = lane >> 2;
  const int swzS = (rA & 3) ^ ((rA >> 2) & 3);
  const int cA = ((lane & 3) ^ swzS) * 8;

  // fragment-read swizzle (matches staging)
  const int fr = lane & 15;
  const int fs = (fr & 3) ^ ((fr >> 2) & 3);
  const int fk = ((lane >> 4) ^ fs) * 8;

  f32x4 acc[8][4];
  #pragma unroll
  for (int tm = 0; tm < 8; ++tm)
    #pragma unroll
    for (int tn = 0; tn < 4; ++tn) acc[tm][tn] = {0.f, 0.f, 0.f, 0.f};

  // stage one BK=32 K-panel (A 256x32 + B 256x32) into ring slot: 4 loads/lane
  auto stage = [&](int kt, int slot) {
    half_t* As = lds + slot * 16384;
    half_t* Bs = As + 8192;
    const int koff = kt * 32 + cA;
    #pragma unroll
    for (int i = 0; i < 2; ++i) {
      int row = i * 128 + wave * 16;
      gl2lds16(A + (size_t)(bm + row + rA) * 512 + koff, As + row * 32);
      gl2lds16(B + (size_t)(bn + row + rA) * 512 + koff, Bs + row * 32);
    }
  };

  // prologue: 3 tiles in flight before first compute
  stage(0, 0);
  stage(1, 1);
  stage(2, 2);

  for (int kt = 0; kt < 16; ++kt) {
    // counted wait: drains tile kt's staging loads (issued 3 boundaries ago),
    // keeps the newest 2 tiles' loads in flight. Tail ramps 8 -> 4 -> 0.
    if (kt < 14)       asm volatile("s_waitcnt vmcnt(8)" ::: "memory");
    else if (kt == 14) asm volatile("s_waitcnt vmcnt(4)" ::: "memory");
    else               asm volatile("s_waitcnt vmcnt(0)" ::: "memory");
    __builtin_amdgcn_s_barrier();
    asm volatile("" ::: "memory");

    if (kt + 3 < 16) stage(kt + 3, (kt + 3) & 3);

    const half_t* As = lds + (kt & 3) * 16384;
    const half_t* Bs = As + 8192;

    halfx8 bf[4];
    #pragma unroll
    for (int tn = 0; tn < 4; ++tn)
      bf[tn] = *(const halfx8*)(Bs + (wn * 64 + tn * 16 + fr) * 32 + fk);

    __builtin_amdgcn_s_setprio(1);
    #pragma unroll
    for (int tm = 0; tm < 8; ++tm) {
      halfx8 af = *(const halfx8*)(As + (wm * 128 + tm * 16 + fr) * 32 + fk);
      #pragma unroll
      for (int tn = 0; tn < 4; ++tn)
        acc[tm][tn] = __builtin_amdgcn_mfma_f32_16x16x32_f16(af, bf[tn], acc[tm][tn], 0, 0, 0);
    }
    __builtin_amdgcn_s_setprio(0);
  }

  // epilogue: fp16 bounce through LDS for coalesced halfx8 stores (2 passes of
  // 128 rows, stride 264 to de-conflict). lds is free after the K-loop.
  half_t* Cs = lds;
  const int rq = (lane >> 4) * 4;
  const int cl0 = lane & 15;
  #pragma unroll 1
  for (int mh = 0; mh < 2; ++mh) {
    __syncthreads();
    if (wm == mh) {
      #pragma unroll
      for (int tm = 0; tm < 8; ++tm)
        #pragma unroll
        for (int tn = 0; tn < 4; ++tn) {
          int cl = wn * 64 + tn * 16 + cl0;
          #pragma unroll
          for (int rr = 0; rr < 4; ++rr)
            Cs[(tm * 16 + rq + rr) * 264 + cl] = (half_t)acc[tm][tn][rr];
        }
    }
    __syncthreads();
    #pragma unroll
    for (int i = 0; i < 8; ++i) {
      int rr2 = i * 16 + (tid >> 5);
      int cc = (tid & 31) * 8;
      halfx8 v = *(const halfx8*)(Cs + rr2 * 264 + cc);
      *(halfx8*)(C + (size_t)(bm + mh * 128 + rr2) * 1024 + bn + cc) = v;
    }
  }
}

// ============================================================
// final GEMM, split-K=4 in one dispatch (round-14 verified)
// ============================================================
__global__ __launch_bounds__(256) void gemm_f16_splitk(
    const half_t* __restrict__ A, const half_t* __restrict__ B,
    float* __restrict__ Cp, const float* __restrict__ bias1, const float* __restrict__ bias2,
    int M, int N) {
  constexpr int SA = 2112;
  __shared__ half_t lds[(64 + 64) * 64];
  half_t* A_s = lds;
  half_t* B_s = A_s + 2 * 64 * 32;

  const int part = blockIdx.y;
  const int koff = part ? 576 + (part - 1) * 512 : 0;
  const int kend = part ? 512 : 576;
  const half_t* Ap = A + koff;
  const half_t* Bp = B + koff;
  float* C = Cp + (size_t)part * M * N;

  const int R = M / 64, NT = N / 64;
  int b = blockIdx.x;
  int xcd = b & 7, q = b >> 3;
  int ct = q % NT, rg = q / NT;
  int r = rg * 8 + xcd;
  if (r >= R) return;

  const int tid = threadIdx.x;
  const int wave = tid >> 6, lane = tid & 63;
  const int wm = wave >> 1, wn = wave & 1;
  const int bm = r * 64, bn = ct * 64;

  const int rA = lane >> 2;
  const int swz = (rA & 3) ^ ((rA >> 2) & 3);
  const int cA = ((lane & 3) ^ swz) * 8;

  f32x4 acc[2][2];
  #pragma unroll
  for (int tm = 0; tm < 2; ++tm)
    #pragma unroll
    for (int tn = 0; tn < 2; ++tn) acc[tm][tn] = {0.f, 0.f, 0.f, 0.f};

  for (int k0 = 0; k0 < kend; k0 += 64) {
    #pragma unroll
    for (int p = 0; p < 2; ++p) {
      int kk = k0 + p * 32;
      int row = wave * 16;
      gl2lds16(Ap + (size_t)(bm + row + rA) * SA + kk + cA,
               A_s + p * 64 * 32 + row * 32);
      gl2lds16(Bp + (size_t)(bn + row + rA) * SA + kk + cA,
               B_s + p * 64 * 32 + row * 32);
    }
    __syncthreads();
    const int fr = lane & 15;
    const int fs = (fr & 3) ^ ((fr >> 2) & 3);
    const int fk = ((lane >> 4) ^ fs) * 8;
    #pragma unroll
    for (int p = 0; p < 2; ++p) {
      const int pA = p * 64 * 32, pB = p * 64 * 32;
      halfx8 af[2], bf[2];
      #pragma unroll
      for (int tm = 0; tm < 2; ++tm) {
        int rr = (wm * 2 + tm) * 16 + fr;
        af[tm] = *(const halfx8*)(A_s + pA + rr * 32 + fk);
      }
      #pragma unroll
      for (int tn = 0; tn < 2; ++tn) {
        int rr = (wn * 2 + tn) * 16 + fr;
        bf[tn] = *(const halfx8*)(B_s + pB + rr * 32 + fk);
      }
      #pragma unroll
      for (int tm = 0; tm < 2; ++tm)
        #pragma unroll
        for (int tn = 0; tn < 2; ++tn)
          acc[tm][tn] = __builtin_amdgcn_mfma_f32_16x16x32_f16(af[tm], bf[tn], acc[tm][tn], 0, 0, 0);
    }
    __syncthreads();
  }

  const int col0 = lane & 15, rq = (lane >> 4) * 4;
  #pragma unroll
  for (int tm = 0; tm < 2; ++tm)
    #pragma unroll
    for (int tn = 0; tn < 2; ++tn) {
      int col = bn + (wn * 2 + tn) * 16 + col0;
      float badd = (part == 0) ? (bias1[col] + bias2[col]) : 0.f;
      #pragma unroll
      for (int rr = 0; rr < 4; ++rr) {
        int row = bm + (wm * 2 + tm) * 16 + rq + rr;
        C[(size_t)row * N + col] = acc[tm][tn][rr] + badd;
      }
    }
}

// ============================================================
// GAT layer 2, 512 threads (8 waves)
// ============================================================
__global__ __launch_bounds__(512) void gat2_kernel(
    const half_t* __restrict__ xlr, const int* __restrict__ src, const int* __restrict__ dst,
    const float* __restrict__ ea, const float* __restrict__ We,
    const float* __restrict__ att, const float* __restrict__ bias,
    half_t* __restrict__ h2, int g0) {
  __shared__ alignas(16) float We_s[3 * 512];
  __shared__ alignas(16) float att_s[512];
  __shared__ float b_s[HID];
  __shared__ float easX[EPG], easY[EPG], easZ[EPG];
  __shared__ float logit_s[HEADS * 65];
  __shared__ int sloc[EPG], dloc[EPG], deg[N_NODES], start[N_NODES], fill[N_NODES], elist[EPG];

  const int g = g0 + blockIdx.x, tid = threadIdx.x;
  const int nb = g * N_NODES, eb = g * EPG;
  const int lb = blockIdx.x * N_NODES;
  const int wave = tid >> 6, lane = tid & 63;

  for (int i = tid; i < 1536; i += 512) We_s[i] = We[i];
  if (tid < 512) att_s[tid] = att[tid];
  if (tid < HID) b_s[tid] = bias[tid];
  if (tid < EPG) {
    easX[tid] = ea[(eb + tid) * 3 + 0];
    easY[tid] = ea[(eb + tid) * 3 + 1];
    easZ[tid] = ea[(eb + tid) * 3 + 2];
    sloc[tid] = src[eb + tid] - nb;
    dloc[tid] = dst[eb + tid] - nb;
  }
  if (tid < N_NODES) { deg[tid] = 0; fill[tid] = 0; }
  __syncthreads();
  if (tid < EPG) atomicAdd(&deg[dloc[tid]], 1);
  __syncthreads();
  if (tid == 0) { int a = 0; for (int n = 0; n < N_NODES; ++n) { start[n] = a; a += deg[n]; } }
  __syncthreads();
  if (tid < EPG) { int d = dloc[tid]; int p = atomicAdd(&fill[d], 1); elist[start[d] + p] = tid; }
  __syncthreads();

  const int j0 = lane * 8;
  float w0[8], w1[8], w2[8], at8[8];
  #pragma unroll
  for (int q = 0; q < 8; ++q) {
    w0[q] = We_s[j0 + q];
    w1[q] = We_s[512 + j0 + q];
    w2[q] = We_s[1024 + j0 + q];
    at8[q] = att_s[j0 + q];
  }

  // logits: one wave per edge (8 iterations at 8 waves)
  for (int e = wave; e < EPG; e += 8) {
    int s = sloc[e], d = dloc[e];
    halfx8 xlv = *((const halfx8*)(xlr + (size_t)(lb + s) * 1024) + lane);
    halfx8 xrv = *((const halfx8*)(xlr + (size_t)(lb + d) * 1024 + 512) + lane);
    float e0 = easX[e], e1 = easY[e], e2 = easZ[e];
    float acc = 0.f;
    #pragma unroll
    for (int q = 0; q < 8; ++q) {
      float v = (float)xlv[q] + (float)xrv[q] + e0 * w0[q] + e1 * w1[q] + e2 * w2[q];
      acc += lreluf_(v) * at8[q];
    }
    acc += __shfl_xor(acc, 1, 64);
    acc += __shfl_xor(acc, 2, 64);
    acc += __shfl_xor(acc, 4, 64);
    if ((lane & 7) == 0) logit_s[(lane >> 3) * 65 + e] = acc;
  }
  __syncthreads();

  // softmax: one pass, h = tid>>6, n = lane (skip n>=33)
  {
    int h = tid >> 6, n = tid & 63;
    if (n < N_NODES) {
      int s0 = start[n], dn = deg[n];
      float mx = -1e30f;
      for (int i = 0; i < dn; ++i) mx = fmaxf(mx, logit_s[h * 65 + elist[s0 + i]]);
      float den = 0.f;
      for (int i = 0; i < dn; ++i) den += expf(logit_s[h * 65 + elist[s0 + i]] - mx);
      float inv = 1.f / (den + 1e-16f);
      for (int i = 0; i < dn; ++i) {
        int e = elist[s0 + i];
        logit_s[h * 65 + e] = expf(logit_s[h * 65 + e] - mx) * inv;
      }
    }
  }
  __syncthreads();

  // aggregation: wave-task n (5 iterations at 8 waves), lane = HID channel
  for (int n = wave; n < N_NODES; n += 8) {
    float acc = 0.f;
    int s0 = start[n], dn = deg[n];
    for (int i = 0; i < dn; ++i) {
      int e = elist[s0 + i], s = sloc[e];
      const half_t* row = xlr + (size_t)(lb + s) * 1024 + lane;
      #pragma unroll
      for (int h = 0; h < 8; ++h)
        acc += logit_s[h * 65 + e] * (float)row[h * 64];
    }
    float v = eluf_(acc * 0.125f + b_s[lane]);
    h2[(size_t)(nb + n) * HID + lane] = (half_t)v;
  }
}

// ============================================================
// Fused LSTM1 + x2 + LSTM2 + FC (round-14 verified)
// ============================================================
__global__ __launch_bounds__(1024, 4) void lstm_all(
    const float* __restrict__ X0, const float* __restrict__ X1,
    const float* __restrict__ X2p, const float* __restrict__ X3,
    const float* __restrict__ Whh1,
    const float* __restrict__ Wih2, const float* __restrict__ bih2,
    const float* __restrict__ bhh2, const float* __restrict__ Whh2,
    const float* __restrict__ fcW, const float* __restrict__ fcb,
    float* __restrict__ out) {
  __shared__ float hs1[LSTM1_H], cs1[LSTM1_H], p1[512], gs1[512];
  __shared__ float Y1s[SEQ][LSTM1_H];
  __shared__ float hs2[LSTM2_H], cs2[LSTM2_H], p2[4 * 256], gs2[256];
  const int tid = threadIdx.x, b = blockIdx.x;
  const int j = tid & 511, half = tid >> 9;

  float4 w1[16];
  {
    const float4* wp = (const float4*)(Whh1 + (size_t)j * LSTM1_H + half * 64);
    #pragma unroll
    for (int q = 0; q < 16; ++q) w1[q] = wp[q];
  }
  if (tid < LSTM1_H) { hs1[tid] = 0.f; cs1[tid] = 0.f; }
  __syncthreads();
  for (int t = 0; t < SEQ; ++t) {
    const float* hb = hs1 + half * 64;
    float acc = 0.f;
    #pragma unroll
    for (int q = 0; q < 16; ++q) {
      acc += w1[q].x * hb[4 * q] + w1[q].y * hb[4 * q + 1]
           + w1[q].z * hb[4 * q + 2] + w1[q].w * hb[4 * q + 3];
    }
    if (half) p1[j] = acc;
    __syncthreads();
    if (!half) {
      size_t xo = ((size_t)b * SEQ + t) * 512 + j;
      gs1[j] = acc + p1[j] + X0[xo] + X1[xo] + X2p[xo] + X3[xo];
    }
    __syncthreads();
    if (tid < LSTM1_H) {
      float ig = sigmoidf_(gs1[tid]);
      float fg = sigmoidf_(gs1[LSTM1_H + tid]);
      float gg = tanhf(gs1[2 * LSTM1_H + tid]);
      float og = sigmoidf_(gs1[3 * LSTM1_H + tid]);
      float c = fg * cs1[tid] + ig * gg;
      cs1[tid] = c;
      float h = og * tanhf(c);
      hs1[tid] = h;
      Y1s[t][tid] = h;
    }
    __syncthreads();
  }

  const int j2 = tid & 255, qt = tid >> 8;
  float4 w2x[8], w2h[4];
  {
    const float4* wxp = (const float4*)(Wih2 + (size_t)j2 * LSTM1_H + qt * 32);
    #pragma unroll
    for (int q = 0; q < 8; ++q) w2x[q] = wxp[q];
    const float4* whp = (const float4*)(Whh2 + (size_t)j2 * LSTM2_H + qt * 16);
    #pragma unroll
    for (int q = 0; q < 4; ++q) w2h[q] = whp[q];
  }
  if (tid < LSTM2_H) { hs2[tid] = 0.f; cs2[tid] = 0.f; }
  __syncthreads();
  for (int t = 0; t < SEQ; ++t) {
    const float* y = Y1s[t] + qt * 32;
    const float* hb = hs2 + qt * 16;
    float acc = 0.f;
    #pragma unroll
    for (int q = 0; q < 8; ++q) {
      acc += w2x[q].x * y[4 * q] + w2x[q].y * y[4 * q + 1]
           + w2x[q].z * y[4 * q + 2] + w2x[q].w * y[4 * q + 3];
    }
    #pragma unroll
    for (int q = 0; q < 4; ++q) {
      acc += w2h[q].x * hb[4 * q] + w2h[q].y * hb[4 * q + 1]
           + w2h[q].z * hb[4 * q + 2] + w2h[q].w * hb[4 * q + 3];
    }
    p2[qt * 256 + j2] = acc;
    __syncthreads();
    if (qt == 0)
      gs2[j2] = p2[j2] + p2[256 + j2] + p2[512 + j2] + p2[768 + j2]
              + bih2[j2] + bhh2[j2];
    __syncthreads();
    if (tid < LSTM2_H) {
      float ig = sigmoidf_(gs2[tid]);
      float fg = sigmoidf_(gs2[LSTM2_H + tid]);
      float gg = tanhf(gs2[2 * LSTM2_H + tid]);
      float og = sigmoidf_(gs2[3 * LSTM2_H + tid]);
      float c = fg * cs2[tid] + ig * gg;
      cs2[tid] = c;
      hs2[tid] = og * tanhf(c);
    }
    __syncthreads();
  }
  if (tid < 4) {
    float acc = fcb[tid];
    #pragma unroll
    for (int k = 0; k < LSTM2_H; ++k) acc += fcW[tid * LSTM2_H + k] * hs2[k];
    out[b * 4 + tid] = acc;
  }
}

// ============================================================
extern "C" void kernel_launch(void* const* d_in, const int* in_sizes, int n_in,
                              void* d_out, int out_size, void* d_ws, size_t ws_size,
                              hipStream_t stream) {
  const float* x       = (const float*)d_in[0];
  const int*   eidx    = (const int*)d_in[1];
  const float* eattr   = (const float*)d_in[2];
  const float* g1_Wl   = (const float*)d_in[3];
  const float* g1_Wr   = (const float*)d_in[4];
  const float* g1_We   = (const float*)d_in[5];
  const float* g1_att  = (const float*)d_in[6];
  const float* g1_b    = (const float*)d_in[7];
  const float* g2_Wl   = (const float*)d_in[8];
  const float* g2_Wr   = (const float*)d_in[9];
  const float* g2_We   = (const float*)d_in[10];
  const float* g2_att  = (const float*)d_in[11];
  const float* g2_b    = (const float*)d_in[12];
  const float* l1_Wih  = (const float*)d_in[13];
  const float* l1_Whh  = (const float*)d_in[14];
  const float* l1_bih  = (const float*)d_in[15];
  const float* l1_bhh  = (const float*)d_in[16];
  const float* l2_Wih  = (const float*)d_in[17];
  const float* l2_Whh  = (const float*)d_in[18];
  const float* l2_bih  = (const float*)d_in[19];
  const float* l2_bhh  = (const float*)d_in[20];
  const float* fc_W    = (const float*)d_in[21];
  const float* fc_b    = (const float*)d_in[22];
  float* out = (float*)d_out;

  const int* src = eidx;
  const int* dst = eidx + E_EDGES;

  // ---- runtime-adaptive chunking ----
  // NOTE: candidate "4" removed (chunk_n = 12672 not divisible by BM=256 of
  // the new gemm256). Measured runs use nchunks = 1.
  const int cand[4] = {1, 2, 3, 6};
  int nchunks = 0;
  half_t *h1 = nullptr, *xlr2c = nullptr, *h2 = nullptr, *B2 = nullptr, *W1f = nullptr;
  float *X1p = nullptr;
  int chunk_g = 0, chunk_n = 0;
  for (int ci = 0; ci < 4; ++ci) {
    int C = cand[ci];
    int CG = G_GRAPHS / C, CN = CG * N_NODES;
    char* p = (char*)d_ws;
    auto alloc = [&](size_t bytes) { char* r = p; p += (bytes + 255) & ~(size_t)255; return r; };
    half_t* t_h1    = (half_t*)alloc((size_t)CN * HC * 2);
    half_t* t_xlr2c = (half_t*)alloc((size_t)CN * 1024 * 2);
    half_t* t_h2    = (half_t*)alloc((size_t)G_GRAPHS * 2112 * 2);
    half_t* t_B2    = (half_t*)alloc((size_t)1024 * 512 * 2);
    half_t* t_W1f   = (half_t*)alloc((size_t)512 * 2112 * 2);
    float*  t_X1p   = (float*)alloc((size_t)4 * G_GRAPHS * 512 * 4);
    if ((size_t)(p - (char*)d_ws) <= ws_size) {
      nchunks = C; chunk_g = CG; chunk_n = CN;
      h1 = t_h1; xlr2c = t_xlr2c; h2 = t_h2; B2 = t_B2; W1f = t_W1f;
      X1p = t_X1p;
      break;
    }
  }
  if (nchunks == 0) return;   // guard: zero output instead of memory fault

  for (int c = 0; c < nchunks; ++c) {
    int g0 = c * chunk_g;
    int extra = (c == 0) ? CONV_BLOCKS : 0;
    gat1_kernel<<<chunk_g + extra, 512, 0, stream>>>(
        x, src, dst, eattr, g1_Wl, g1_Wr, g1_We, g1_att, g1_b, h1, g0, chunk_g,
        g2_Wl, g2_Wr, B2, l1_Wih, W1f);
    int R = chunk_n / 256;
    int gblocks = 8 * ((R + 7) / 8) * 4;
    gemm256<<<gblocks, 512, 0, stream>>>(h1, B2, xlr2c, chunk_n);
    gat2_kernel<<<chunk_g, 512, 0, stream>>>(xlr2c, src, dst, eattr, g2_We,
                                             g2_att, g2_b, h2, g0);
  }

  // X1 partials = h2 @ l1_Wih^T (+biases in part 0), split-K=4, one dispatch
  {
    dim3 grid(192, 4);
    gemm_f16_splitk<<<grid, 256, 0, stream>>>(h2, W1f, X1p, l1_bih, l1_bhh,
                                              G_GRAPHS, 512);
  }

  // fused LSTM1 + x2 + LSTM2 + FC
  {
    size_t PS = (size_t)G_GRAPHS * 512;
    lstm_all<<<BATCH, 1024, 0, stream>>>(X1p, X1p + PS, X1p + 2 * PS, X1p + 3 * PS,
                                         l1_Whh, l2_Wih, l2_bih, l2_bhh, l2_Whh,
                                         fc_W, fc_b, out);
  }
}

// Round 2
// 354.153 us; speedup vs baseline: 1.0150x; 1.0150x over previous
//
#include <hip/hip_runtime.h>
#include <math.h>

// ---- problem constants ----
#define N_NODES 33
#define SEQ 24
#define BATCH 64
#define G_GRAPHS (BATCH * SEQ)          // 1536
#define EPG 64
#define E_EDGES (G_GRAPHS * EPG)        // 98304
#define N_TOTAL (G_GRAPHS * N_NODES)    // 50688
#define HID 64
#define HEADS 8
#define HC (HID * HEADS)                // 512
#define LSTM1_H 128
#define LSTM2_H 64
#define NEG_SLOPE 0.2f
// conv fused into gat1 chunk 0: 128 transpose tiles + 264 W1f blocks
#define CONV_BLOCKS (128 + 264)

__device__ __forceinline__ float sigmoidf_(float x) { return 1.f / (1.f + expf(-x)); }
__device__ __forceinline__ float eluf_(float x) { return x > 0.f ? x : expm1f(x); }
__device__ __forceinline__ float lreluf_(float x) { return x > 0.f ? x : NEG_SLOPE * x; }

typedef __attribute__((ext_vector_type(4))) float f32x4;
typedef _Float16 half_t;
typedef __attribute__((ext_vector_type(8))) _Float16 halfx8;

__device__ __forceinline__ void gl2lds16(const void* g, void* l) {
  __builtin_amdgcn_global_load_lds(
      (__attribute__((address_space(1))) const unsigned int*)g,
      (__attribute__((address_space(3))) unsigned int*)l, 16, 0, 0);
}

// ============================================================
// GAT layer 1, 512 threads (8 waves). Blocks >= gat_blocks do the one-time
// fp16 weight conversion: 128 LDS-transpose tiles + 264 elementwise W1f blocks.
// ============================================================
__global__ __launch_bounds__(512) void gat1_kernel(
    const float* __restrict__ x, const int* __restrict__ src, const int* __restrict__ dst,
    const float* __restrict__ ea, const float* __restrict__ Wl, const float* __restrict__ Wr,
    const float* __restrict__ We, const float* __restrict__ att, const float* __restrict__ bias,
    half_t* __restrict__ h1, int g0, int gat_blocks,
    const float* __restrict__ g2Wl, const float* __restrict__ g2Wr,
    half_t* __restrict__ B2, const float* __restrict__ W1, half_t* __restrict__ W1f) {
  const int tid = threadIdx.x;

  __shared__ alignas(16) float Wl_s[2 * 512];
  __shared__ alignas(16) float Wr_s[2 * 512];
  __shared__ alignas(16) float We_s[3 * 512];
  __shared__ alignas(16) float att_s[512];
  __shared__ float xs0_s[N_NODES + 1], xs1_s[N_NODES + 1];
  __shared__ float easX[EPG], easY[EPG], easZ[EPG];
  __shared__ float logit_s[HEADS * 65];
  __shared__ int sloc[EPG], dloc[EPG], deg[N_NODES], start[N_NODES], fill[N_NODES], elist[EPG];
  __shared__ float tr[64 * 65];          // transpose tile (conv path)

  if ((int)blockIdx.x >= gat_blocks) {
    int cb = blockIdx.x - gat_blocks;
    if (cb < 128) {
      // transpose B2[n][k] = [Wl|Wr][k][n], 64x64 tile, coalesced both ways
      int kt = cb & 7, nt = cb >> 3;
      int k0 = kt * 64, n0 = nt * 64;
      int r = tid >> 6, c = tid & 63;
      #pragma unroll
      for (int rr = 0; rr < 8; ++rr) {
        int kl = rr * 8 + r;
        int n = n0 + c;
        float v = (n < 512) ? g2Wl[(size_t)(k0 + kl) * 512 + n]
                            : g2Wr[(size_t)(k0 + kl) * 512 + n - 512];
        tr[kl * 65 + c] = v;
      }
      __syncthreads();
      #pragma unroll
      for (int rr = 0; rr < 8; ++rr) {
        int nl = rr * 8 + r;
        B2[(size_t)(n0 + nl) * 512 + k0 + c] = (half_t)tr[c * 65 + nl];
      }
    } else {
      int base = (cb - 128) * 4096 + tid;
      #pragma unroll
      for (int i = 0; i < 8; ++i) {
        int idx = base + i * 512;
        if (idx < 512 * 2112) W1f[idx] = (half_t)W1[idx];
      }
    }
    return;
  }

  const int g = g0 + blockIdx.x;
  const int nb = g * N_NODES, eb = g * EPG;
  const int lb = blockIdx.x * N_NODES;

  for (int i = tid; i < 1024; i += 512) { Wl_s[i] = Wl[i]; Wr_s[i] = Wr[i]; }
  for (int i = tid; i < 1536; i += 512) We_s[i] = We[i];
  if (tid < 512) att_s[tid] = att[tid];
  if (tid < 2 * N_NODES) {
    float v = x[nb * 2 + tid];
    if (tid & 1) xs1_s[tid >> 1] = v; else xs0_s[tid >> 1] = v;
  }
  if (tid < EPG) {
    easX[tid] = ea[(eb + tid) * 3 + 0];
    easY[tid] = ea[(eb + tid) * 3 + 1];
    easZ[tid] = ea[(eb + tid) * 3 + 2];
    sloc[tid] = src[eb + tid] - nb;
    dloc[tid] = dst[eb + tid] - nb;
  }
  if (tid < N_NODES) { deg[tid] = 0; fill[tid] = 0; }
  __syncthreads();
  if (tid < EPG) atomicAdd(&deg[dloc[tid]], 1);
  __syncthreads();
  if (tid == 0) { int a = 0; for (int n = 0; n < N_NODES; ++n) { start[n] = a; a += deg[n]; } }
  __syncthreads();
  if (tid < EPG) { int d = dloc[tid]; int p = atomicAdd(&fill[d], 1); elist[start[d] + p] = tid; }

  // logits: one pass, h = tid>>6 (wave-uniform), e = lane
  {
    int h = tid >> 6, e = tid & 63;
    int s = sloc[e], d = dloc[e];
    float xs0 = xs0_s[s], xs1 = xs1_s[s], xd0 = xs0_s[d], xd1 = xs1_s[d];
    float e0 = easX[e], e1 = easY[e], e2 = easZ[e];
    float acc = 0.f;
    int base = h * 64;
    #pragma unroll
    for (int c4 = 0; c4 < 16; ++c4) {
      int j = base + c4 * 4;
      f32x4 wl0 = *(const f32x4*)(Wl_s + j);
      f32x4 wl1 = *(const f32x4*)(Wl_s + 512 + j);
      f32x4 wr0 = *(const f32x4*)(Wr_s + j);
      f32x4 wr1 = *(const f32x4*)(Wr_s + 512 + j);
      f32x4 we0 = *(const f32x4*)(We_s + j);
      f32x4 we1 = *(const f32x4*)(We_s + 512 + j);
      f32x4 we2 = *(const f32x4*)(We_s + 1024 + j);
      f32x4 at  = *(const f32x4*)(att_s + j);
      #pragma unroll
      for (int q = 0; q < 4; ++q) {
        float v = xs0 * wl0[q] + xs1 * wl1[q]
                + xd0 * wr0[q] + xd1 * wr1[q]
                + e0 * we0[q] + e1 * we1[q] + e2 * we2[q];
        acc += lreluf_(v) * at[q];
      }
    }
    logit_s[h * 65 + e] = acc;
  }
  __syncthreads();

  // segment softmax: one pass, h = tid>>6, n = lane (skip n>=33)
  {
    int h = tid >> 6, n = tid & 63;
    if (n < N_NODES) {
      int s0 = start[n], dn = deg[n];
      float mx = -1e30f;
      for (int i = 0; i < dn; ++i) mx = fmaxf(mx, logit_s[h * 65 + elist[s0 + i]]);
      float den = 0.f;
      for (int i = 0; i < dn; ++i) den += expf(logit_s[h * 65 + elist[s0 + i]] - mx);
      float inv = 1.f / (den + 1e-16f);
      for (int i = 0; i < dn; ++i) {
        int e = elist[s0 + i];
        logit_s[h * 65 + e] = expf(logit_s[h * 65 + e] - mx) * inv;
      }
    }
  }
  __syncthreads();

  // aggregation: task = (n, 8-channel block); n = t>>6 wave-uniform, jb = lane
  for (int t = tid; t < N_NODES * 64; t += 512) {
    int n = t >> 6, jb = t & 63;
    int j0 = jb * 8, h = jb >> 3;
    f32x4 wa0 = *(const f32x4*)(Wl_s + j0);
    f32x4 wa1 = *(const f32x4*)(Wl_s + j0 + 4);
    f32x4 wb0 = *(const f32x4*)(Wl_s + 512 + j0);
    f32x4 wb1 = *(const f32x4*)(Wl_s + 512 + j0 + 4);
    float acc[8] = {};
    int s0 = start[n], dn = deg[n];
    for (int i = 0; i < dn; ++i) {
      int e = elist[s0 + i]; int s = sloc[e];
      float a = logit_s[h * 65 + e];
      float ax0 = a * xs0_s[s], ax1 = a * xs1_s[s];
      #pragma unroll
      for (int q = 0; q < 4; ++q) {
        acc[q]     += ax0 * wa0[q] + ax1 * wb0[q];
        acc[4 + q] += ax0 * wa1[q] + ax1 * wb1[q];
      }
    }
    f32x4 b0 = *(const f32x4*)(bias + j0);
    f32x4 b1 = *(const f32x4*)(bias + j0 + 4);
    halfx8 vh;
    #pragma unroll
    for (int cc = 0; cc < 8; ++cc) {
      float bb = (cc < 4) ? b0[cc] : b1[cc - 4];
      vh[cc] = (half_t)eluf_(acc[cc] + bb);
    }
    *(halfx8*)(h1 + (size_t)(lb + n) * HC + j0) = vh;
  }
}

// ============================================================
// Main GEMM, round-17: full 8-phase schedule (T3+T4+T5, m201 template).
// 256x256 tile, BK=64, 512 threads (8 waves, 2Mx4N), 2-stage LDS dbuf
// (128 KiB). Each K-tile = 4 C-quadrant phases of 16 MFMA; each phase
// stages exactly ONE half-tile (2 gl2lds per wave). Steady-state stage
// order (verified hazard ledger):
//   P1: T(t1).Ah0->s1  P2: T(t1).Ah1->s1  P3: T(t0+2).Bh0->s0
//   P4: T(t0+2).Bh1->s0 [vmcnt(4)]        P5: T(t0+2).Ah0->s0
//   P6: T(t0+2).Ah1->s0 P7: T(t1+2).Bh0->s1 P8: T(t1+2).Bh1->s1 [vmcnt(4)]
// B-halves of a stage are read only in phase0 of their tile (held in bf[]),
// A-halves through phase3 -> every overwrite is >=1 full barrier after the
// last read; every half-tile has >=3 phases load->use distance.
// vmcnt never drains to 0 until the final tile. 8-slot XOR swizzle
// (chunk ^= row&7 in 128B rows): ds_read_b128 structurally conflict-free.
// ============================================================
#define PHASE_BAR() do { asm volatile("" ::: "memory"); \
  __builtin_amdgcn_s_barrier(); asm volatile("" ::: "memory"); } while (0)

#define LDA8(S, rr, kc) \
  (*(const halfx8*)((S) + (rr) * 64 + (((kc) ^ ((rr) & 7)) << 3)))

#define READ_B(Bs)                                                        \
  _Pragma("unroll")                                                       \
  for (int tn = 0; tn < 4; ++tn)                                          \
    _Pragma("unroll")                                                     \
    for (int ks = 0; ks < 2; ++ks)                                        \
      bf[tn][ks] = LDA8(Bs, wn * 64 + tn * 16 + fr, ks * 4 + kq);

#define READ_A(As, q)                                                     \
  _Pragma("unroll")                                                       \
  for (int tl = 0; tl < 2; ++tl)                                          \
    _Pragma("unroll")                                                     \
    for (int ks = 0; ks < 2; ++ks)                                        \
      af[tl][ks] = LDA8(As, wm * 128 + ((q) * 2 + tl) * 16 + fr, ks * 4 + kq);

#define MFMA_Q(q)                                                         \
  __builtin_amdgcn_s_setprio(1);                                          \
  _Pragma("unroll")                                                       \
  for (int ks = 0; ks < 2; ++ks)                                          \
    _Pragma("unroll")                                                     \
    for (int tl = 0; tl < 2; ++tl)                                        \
      _Pragma("unroll")                                                   \
      for (int tn = 0; tn < 4; ++tn)                                      \
        acc[(q) * 2 + tl][tn] = __builtin_amdgcn_mfma_f32_16x16x32_f16(   \
            af[tl][ks], bf[tn][ks], acc[(q) * 2 + tl][tn], 0, 0, 0);      \
  __builtin_amdgcn_s_setprio(0);

__global__ __launch_bounds__(512, 2) void gemm256_8p(
    const half_t* __restrict__ A, const half_t* __restrict__ B,
    half_t* __restrict__ C, int M) {
  __shared__ alignas(16) half_t lds[65536];   // 2 stages x (A 256x64 + B 256x64)

  const int R = M >> 8;
  int b = blockIdx.x;
  int xcd = b & 7, q = b >> 3;
  int ct = q & 3, rg = q >> 2;          // NT = 1024/256 = 4 col tiles
  int r = rg * 8 + xcd;
  if (r >= R) return;

  const int tid = threadIdx.x;
  const int wave = tid >> 6, lane = tid & 63;
  const int wm = wave >> 2, wn = wave & 3;       // 2M x 4N wave grid
  const int bm = r << 8, bn = ct << 8;

  // staging: lane -> row (lane>>3) of 8, chunk (lane&7)^row  (8-slot XOR)
  const int rl = lane >> 3;
  const int gc = ((lane & 7) ^ rl) << 3;
  // fragment read: lane -> row fr, k-quarter kq
  const int fr = lane & 15;
  const int kq = lane >> 4;

  half_t* A0w = lds;
  half_t* B0w = lds + 16384;
  half_t* A1w = lds + 32768;
  half_t* B1w = lds + 49152;
  const half_t* A0s = A0w;
  const half_t* B0s = B0w;
  const half_t* A1s = A1w;
  const half_t* B1s = B1w;

  f32x4 acc[8][4];
  #pragma unroll
  for (int tm = 0; tm < 8; ++tm)
    #pragma unroll
    for (int tn = 0; tn < 4; ++tn) acc[tm][tn] = {0.f, 0.f, 0.f, 0.f};

  // stage one half-tile (128 rows of one matrix): 2 gl2lds16 per wave
  auto stage_ht = [&](const half_t* __restrict__ G, int rowbase, int kt, int h,
                      half_t* Ls) {
    const int r0 = h * 128 + wave * 16;
    const half_t* gp = G + (size_t)(rowbase + r0 + rl) * 512 + kt * 64 + gc;
    gl2lds16(gp, Ls + r0 * 64);
    gl2lds16(gp + (size_t)8 * 512, Ls + (r0 + 8) * 64);
  };

  // ---- prologue: T0 (4 ht) then T1.B (2 ht); drain T0, keep T1.B flying ----
  stage_ht(B, bn, 0, 0, B0w);
  stage_ht(B, bn, 0, 1, B0w);
  stage_ht(A, bm, 0, 0, A0w);
  stage_ht(A, bm, 0, 1, A0w);
  stage_ht(B, bn, 1, 0, B1w);
  stage_ht(B, bn, 1, 1, B1w);
  asm volatile("s_waitcnt vmcnt(4)" ::: "memory");
  PHASE_BAR();

  #pragma unroll
  for (int j = 0; j < 4; ++j) {
    const int t1 = 2 * j + 1;
    const bool nl = (j < 3);
    halfx8 bf[4][2], af[2][2];

    // ---------- tile t0 = 2j from stage0 ----------
    // P1
    READ_B(B0s); READ_A(A0s, 0);
    stage_ht(A, bm, t1, 0, A1w);
    PHASE_BAR(); MFMA_Q(0); PHASE_BAR();
    // P2
    READ_A(A0s, 1);
    stage_ht(A, bm, t1, 1, A1w);
    PHASE_BAR(); MFMA_Q(1); PHASE_BAR();
    // P3
    READ_A(A0s, 2);
    if (nl) stage_ht(B, bn, t1 + 1, 0, B0w);
    PHASE_BAR(); MFMA_Q(2); PHASE_BAR();
    // P4  (drain: T(t1) must be complete for P5)
    READ_A(A0s, 3);
    if (nl) {
      stage_ht(B, bn, t1 + 1, 1, B0w);
      asm volatile("s_waitcnt vmcnt(4)" ::: "memory");
    } else {
      asm volatile("s_waitcnt vmcnt(0)" ::: "memory");
    }
    PHASE_BAR(); MFMA_Q(3); PHASE_BAR();

    // ---------- tile t1 = 2j+1 from stage1 ----------
    // P5
    READ_B(B1s); READ_A(A1s, 0);
    if (nl) stage_ht(A, bm, t1 + 1, 0, A0w);
    PHASE_BAR(); MFMA_Q(0); PHASE_BAR();
    // P6
    READ_A(A1s, 1);
    if (nl) stage_ht(A, bm, t1 + 1, 1, A0w);
    PHASE_BAR(); MFMA_Q(1); PHASE_BAR();
    // P7
    READ_A(A1s, 2);
    if (nl) stage_ht(B, bn, t1 + 2, 0, B1w);
    PHASE_BAR(); MFMA_Q(2); PHASE_BAR();
    // P8  (drain: T(t0+2) must be complete for next P1)
    READ_A(A1s, 3);
    if (nl) {
      stage_ht(B, bn, t1 + 2, 1, B1w);
      asm volatile("s_waitcnt vmcnt(4)" ::: "memory");
    }
    PHASE_BAR(); MFMA_Q(3); PHASE_BAR();
  }

  // epilogue: fp16 bounce through LDS for coalesced halfx8 stores (2 passes of
  // 128 rows, stride 264 to de-conflict). lds is free after the K-loop.
  half_t* Cs = lds;
  const int rq = (lane >> 4) * 4;
  const int cl0 = lane & 15;
  #pragma unroll 1
  for (int mh = 0; mh < 2; ++mh) {
    __syncthreads();
    if (wm == mh) {
      #pragma unroll
      for (int tm = 0; tm < 8; ++tm)
        #pragma unroll
        for (int tn = 0; tn < 4; ++tn) {
          int cl = wn * 64 + tn * 16 + cl0;
          #pragma unroll
          for (int rr = 0; rr < 4; ++rr)
            Cs[(tm * 16 + rq + rr) * 264 + cl] = (half_t)acc[tm][tn][rr];
        }
    }
    __syncthreads();
    #pragma unroll
    for (int i = 0; i < 8; ++i) {
      int rr2 = i * 16 + (tid >> 5);
      int cc = (tid & 31) * 8;
      halfx8 v = *(const halfx8*)(Cs + rr2 * 264 + cc);
      *(halfx8*)(C + (size_t)(bm + mh * 128 + rr2) * 1024 + bn + cc) = v;
    }
  }
}

// ============================================================
// final GEMM, split-K=4 in one dispatch (round-14 verified)
// ============================================================
__global__ __launch_bounds__(256) void gemm_f16_splitk(
    const half_t* __restrict__ A, const half_t* __restrict__ B,
    float* __restrict__ Cp, const float* __restrict__ bias1, const float* __restrict__ bias2,
    int M, int N) {
  constexpr int SA = 2112;
  __shared__ half_t lds[(64 + 64) * 64];
  half_t* A_s = lds;
  half_t* B_s = A_s + 2 * 64 * 32;

  const int part = blockIdx.y;
  const int koff = part ? 576 + (part - 1) * 512 : 0;
  const int kend = part ? 512 : 576;
  const half_t* Ap = A + koff;
  const half_t* Bp = B + koff;
  float* C = Cp + (size_t)part * M * N;

  const int R = M / 64, NT = N / 64;
  int b = blockIdx.x;
  int xcd = b & 7, q = b >> 3;
  int ct = q % NT, rg = q / NT;
  int r = rg * 8 + xcd;
  if (r >= R) return;

  const int tid = threadIdx.x;
  const int wave = tid >> 6, lane = tid & 63;
  const int wm = wave >> 1, wn = wave & 1;
  const int bm = r * 64, bn = ct * 64;

  const int rA = lane >> 2;
  const int swz = (rA & 3) ^ ((rA >> 2) & 3);
  const int cA = ((lane & 3) ^ swz) * 8;

  f32x4 acc[2][2];
  #pragma unroll
  for (int tm = 0; tm < 2; ++tm)
    #pragma unroll
    for (int tn = 0; tn < 2; ++tn) acc[tm][tn] = {0.f, 0.f, 0.f, 0.f};

  for (int k0 = 0; k0 < kend; k0 += 64) {
    #pragma unroll
    for (int p = 0; p < 2; ++p) {
      int kk = k0 + p * 32;
      int row = wave * 16;
      gl2lds16(Ap + (size_t)(bm + row + rA) * SA + kk + cA,
               A_s + p * 64 * 32 + row * 32);
      gl2lds16(Bp + (size_t)(bn + row + rA) * SA + kk + cA,
               B_s + p * 64 * 32 + row * 32);
    }
    __syncthreads();
    const int fr = lane & 15;
    const int fs = (fr & 3) ^ ((fr >> 2) & 3);
    const int fk = ((lane >> 4) ^ fs) * 8;
    #pragma unroll
    for (int p = 0; p < 2; ++p) {
      const int pA = p * 64 * 32, pB = p * 64 * 32;
      halfx8 af[2], bf[2];
      #pragma unroll
      for (int tm = 0; tm < 2; ++tm) {
        int rr = (wm * 2 + tm) * 16 + fr;
        af[tm] = *(const halfx8*)(A_s + pA + rr * 32 + fk);
      }
      #pragma unroll
      for (int tn = 0; tn < 2; ++tn) {
        int rr = (wn * 2 + tn) * 16 + fr;
        bf[tn] = *(const halfx8*)(B_s + pB + rr * 32 + fk);
      }
      #pragma unroll
      for (int tm = 0; tm < 2; ++tm)
        #pragma unroll
        for (int tn = 0; tn < 2; ++tn)
          acc[tm][tn] = __builtin_amdgcn_mfma_f32_16x16x32_f16(af[tm], bf[tn], acc[tm][tn], 0, 0, 0);
    }
    __syncthreads();
  }

  const int col0 = lane & 15, rq = (lane >> 4) * 4;
  #pragma unroll
  for (int tm = 0; tm < 2; ++tm)
    #pragma unroll
    for (int tn = 0; tn < 2; ++tn) {
      int col = bn + (wn * 2 + tn) * 16 + col0;
      float badd = (part == 0) ? (bias1[col] + bias2[col]) : 0.f;
      #pragma unroll
      for (int rr = 0; rr < 4; ++rr) {
        int row = bm + (wm * 2 + tm) * 16 + rq + rr;
        C[(size_t)row * N + col] = acc[tm][tn][rr] + badd;
      }
    }
}

// ============================================================
// GAT layer 2, 512 threads (8 waves)
// ============================================================
__global__ __launch_bounds__(512) void gat2_kernel(
    const half_t* __restrict__ xlr, const int* __restrict__ src, const int* __restrict__ dst,
    const float* __restrict__ ea, const float* __restrict__ We,
    const float* __restrict__ att, const float* __restrict__ bias,
    half_t* __restrict__ h2, int g0) {
  __shared__ alignas(16) float We_s[3 * 512];
  __shared__ alignas(16) float att_s[512];
  __shared__ float b_s[HID];
  __shared__ float easX[EPG], easY[EPG], easZ[EPG];
  __shared__ float logit_s[HEADS * 65];
  __shared__ int sloc[EPG], dloc[EPG], deg[N_NODES], start[N_NODES], fill[N_NODES], elist[EPG];

  const int g = g0 + blockIdx.x, tid = threadIdx.x;
  const int nb = g * N_NODES, eb = g * EPG;
  const int lb = blockIdx.x * N_NODES;
  const int wave = tid >> 6, lane = tid & 63;

  for (int i = tid; i < 1536; i += 512) We_s[i] = We[i];
  if (tid < 512) att_s[tid] = att[tid];
  if (tid < HID) b_s[tid] = bias[tid];
  if (tid < EPG) {
    easX[tid] = ea[(eb + tid) * 3 + 0];
    easY[tid] = ea[(eb + tid) * 3 + 1];
    easZ[tid] = ea[(eb + tid) * 3 + 2];
    sloc[tid] = src[eb + tid] - nb;
    dloc[tid] = dst[eb + tid] - nb;
  }
  if (tid < N_NODES) { deg[tid] = 0; fill[tid] = 0; }
  __syncthreads();
  if (tid < EPG) atomicAdd(&deg[dloc[tid]], 1);
  __syncthreads();
  if (tid == 0) { int a = 0; for (int n = 0; n < N_NODES; ++n) { start[n] = a; a += deg[n]; } }
  __syncthreads();
  if (tid < EPG) { int d = dloc[tid]; int p = atomicAdd(&fill[d], 1); elist[start[d] + p] = tid; }
  __syncthreads();

  const int j0 = lane * 8;
  float w0[8], w1[8], w2[8], at8[8];
  #pragma unroll
  for (int q = 0; q < 8; ++q) {
    w0[q] = We_s[j0 + q];
    w1[q] = We_s[512 + j0 + q];
    w2[q] = We_s[1024 + j0 + q];
    at8[q] = att_s[j0 + q];
  }

  // logits: one wave per edge (8 iterations at 8 waves)
  for (int e = wave; e < EPG; e += 8) {
    int s = sloc[e], d = dloc[e];
    halfx8 xlv = *((const halfx8*)(xlr + (size_t)(lb + s) * 1024) + lane);
    halfx8 xrv = *((const halfx8*)(xlr + (size_t)(lb + d) * 1024 + 512) + lane);
    float e0 = easX[e], e1 = easY[e], e2 = easZ[e];
    float acc = 0.f;
    #pragma unroll
    for (int q = 0; q < 8; ++q) {
      float v = (float)xlv[q] + (float)xrv[q] + e0 * w0[q] + e1 * w1[q] + e2 * w2[q];
      acc += lreluf_(v) * at8[q];
    }
    acc += __shfl_xor(acc, 1, 64);
    acc += __shfl_xor(acc, 2, 64);
    acc += __shfl_xor(acc, 4, 64);
    if ((lane & 7) == 0) logit_s[(lane >> 3) * 65 + e] = acc;
  }
  __syncthreads();

  // softmax: one pass, h = tid>>6, n = lane (skip n>=33)
  {
    int h = tid >> 6, n = tid & 63;
    if (n < N_NODES) {
      int s0 = start[n], dn = deg[n];
      float mx = -1e30f;
      for (int i = 0; i < dn; ++i) mx = fmaxf(mx, logit_s[h * 65 + elist[s0 + i]]);
      float den = 0.f;
      for (int i = 0; i < dn; ++i) den += expf(logit_s[h * 65 + elist[s0 + i]] - mx);
      float inv = 1.f / (den + 1e-16f);
      for (int i = 0; i < dn; ++i) {
        int e = elist[s0 + i];
        logit_s[h * 65 + e] = expf(logit_s[h * 65 + e] - mx) * inv;
      }
    }
  }
  __syncthreads();

  // aggregation: wave-task n (5 iterations at 8 waves), lane = HID channel
  for (int n = wave; n < N_NODES; n += 8) {
    float acc = 0.f;
    int s0 = start[n], dn = deg[n];
    for (int i = 0; i < dn; ++i) {
      int e = elist[s0 + i], s = sloc[e];
      const half_t* row = xlr + (size_t)(lb + s) * 1024 + lane;
      #pragma unroll
      for (int h = 0; h < 8; ++h)
        acc += logit_s[h * 65 + e] * (float)row[h * 64];
    }
    float v = eluf_(acc * 0.125f + b_s[lane]);
    h2[(size_t)(nb + n) * HID + lane] = (half_t)v;
  }
}

// ============================================================
// Fused LSTM1 + x2 + LSTM2 + FC (round-14 verified)
// ============================================================
__global__ __launch_bounds__(1024, 4) void lstm_all(
    const float* __restrict__ X0, const float* __restrict__ X1,
    const float* __restrict__ X2p, const float* __restrict__ X3,
    const float* __restrict__ Whh1,
    const float* __restrict__ Wih2, const float* __restrict__ bih2,
    const float* __restrict__ bhh2, const float* __restrict__ Whh2,
    const float* __restrict__ fcW, const float* __restrict__ fcb,
    float* __restrict__ out) {
  __shared__ float hs1[LSTM1_H], cs1[LSTM1_H], p1[512], gs1[512];
  __shared__ float Y1s[SEQ][LSTM1_H];
  __shared__ float hs2[LSTM2_H], cs2[LSTM2_H], p2[4 * 256], gs2[256];
  const int tid = threadIdx.x, b = blockIdx.x;
  const int j = tid & 511, half = tid >> 9;

  float4 w1[16];
  {
    const float4* wp = (const float4*)(Whh1 + (size_t)j * LSTM1_H + half * 64);
    #pragma unroll
    for (int q = 0; q < 16; ++q) w1[q] = wp[q];
  }
  if (tid < LSTM1_H) { hs1[tid] = 0.f; cs1[tid] = 0.f; }
  __syncthreads();
  for (int t = 0; t < SEQ; ++t) {
    const float* hb = hs1 + half * 64;
    float acc = 0.f;
    #pragma unroll
    for (int q = 0; q < 16; ++q) {
      acc += w1[q].x * hb[4 * q] + w1[q].y * hb[4 * q + 1]
           + w1[q].z * hb[4 * q + 2] + w1[q].w * hb[4 * q + 3];
    }
    if (half) p1[j] = acc;
    __syncthreads();
    if (!half) {
      size_t xo = ((size_t)b * SEQ + t) * 512 + j;
      gs1[j] = acc + p1[j] + X0[xo] + X1[xo] + X2p[xo] + X3[xo];
    }
    __syncthreads();
    if (tid < LSTM1_H) {
      float ig = sigmoidf_(gs1[tid]);
      float fg = sigmoidf_(gs1[LSTM1_H + tid]);
      float gg = tanhf(gs1[2 * LSTM1_H + tid]);
      float og = sigmoidf_(gs1[3 * LSTM1_H + tid]);
      float c = fg * cs1[tid] + ig * gg;
      cs1[tid] = c;
      float h = og * tanhf(c);
      hs1[tid] = h;
      Y1s[t][tid] = h;
    }
    __syncthreads();
  }

  const int j2 = tid & 255, qt = tid >> 8;
  float4 w2x[8], w2h[4];
  {
    const float4* wxp = (const float4*)(Wih2 + (size_t)j2 * LSTM1_H + qt * 32);
    #pragma unroll
    for (int q = 0; q < 8; ++q) w2x[q] = wxp[q];
    const float4* whp = (const float4*)(Whh2 + (size_t)j2 * LSTM2_H + qt * 16);
    #pragma unroll
    for (int q = 0; q < 4; ++q) w2h[q] = whp[q];
  }
  if (tid < LSTM2_H) { hs2[tid] = 0.f; cs2[tid] = 0.f; }
  __syncthreads();
  for (int t = 0; t < SEQ; ++t) {
    const float* y = Y1s[t] + qt * 32;
    const float* hb = hs2 + qt * 16;
    float acc = 0.f;
    #pragma unroll
    for (int q = 0; q < 8; ++q) {
      acc += w2x[q].x * y[4 * q] + w2x[q].y * y[4 * q + 1]
           + w2x[q].z * y[4 * q + 2] + w2x[q].w * y[4 * q + 3];
    }
    #pragma unroll
    for (int q = 0; q < 4; ++q) {
      acc += w2h[q].x * hb[4 * q] + w2h[q].y * hb[4 * q + 1]
           + w2h[q].z * hb[4 * q + 2] + w2h[q].w * hb[4 * q + 3];
    }
    p2[qt * 256 + j2] = acc;
    __syncthreads();
    if (qt == 0)
      gs2[j2] = p2[j2] + p2[256 + j2] + p2[512 + j2] + p2[768 + j2]
              + bih2[j2] + bhh2[j2];
    __syncthreads();
    if (tid < LSTM2_H) {
      float ig = sigmoidf_(gs2[tid]);
      float fg = sigmoidf_(gs2[LSTM2_H + tid]);
      float gg = tanhf(gs2[2 * LSTM2_H + tid]);
      float og = sigmoidf_(gs2[3 * LSTM2_H + tid]);
      float c = fg * cs2[tid] + ig * gg;
      cs2[tid] = c;
      hs2[tid] = og * tanhf(c);
    }
    __syncthreads();
  }
  if (tid < 4) {
    float acc = fcb[tid];
    #pragma unroll
    for (int k = 0; k < LSTM2_H; ++k) acc += fcW[tid * LSTM2_H + k] * hs2[k];
    out[b * 4 + tid] = acc;
  }
}

// ============================================================
extern "C" void kernel_launch(void* const* d_in, const int* in_sizes, int n_in,
                              void* d_out, int out_size, void* d_ws, size_t ws_size,
                              hipStream_t stream) {
  const float* x       = (const float*)d_in[0];
  const int*   eidx    = (const int*)d_in[1];
  const float* eattr   = (const float*)d_in[2];
  const float* g1_Wl   = (const float*)d_in[3];
  const float* g1_Wr   = (const float*)d_in[4];
  const float* g1_We   = (const float*)d_in[5];
  const float* g1_att  = (const float*)d_in[6];
  const float* g1_b    = (const float*)d_in[7];
  const float* g2_Wl   = (const float*)d_in[8];
  const float* g2_Wr   = (const float*)d_in[9];
  const float* g2_We   = (const float*)d_in[10];
  const float* g2_att  = (const float*)d_in[11];
  const float* g2_b    = (const float*)d_in[12];
  const float* l1_Wih  = (const float*)d_in[13];
  const float* l1_Whh  = (const float*)d_in[14];
  const float* l1_bih  = (const float*)d_in[15];
  const float* l1_bhh  = (const float*)d_in[16];
  const float* l2_Wih  = (const float*)d_in[17];
  const float* l2_Whh  = (const float*)d_in[18];
  const float* l2_bih  = (const float*)d_in[19];
  const float* l2_bhh  = (const float*)d_in[20];
  const float* fc_W    = (const float*)d_in[21];
  const float* fc_b    = (const float*)d_in[22];
  float* out = (float*)d_out;

  const int* src = eidx;
  const int* dst = eidx + E_EDGES;

  // ---- runtime-adaptive chunking (all chunk_n divisible by 256) ----
  const int cand[4] = {1, 2, 3, 6};
  int nchunks = 0;
  half_t *h1 = nullptr, *xlr2c = nullptr, *h2 = nullptr, *B2 = nullptr, *W1f = nullptr;
  float *X1p = nullptr;
  int chunk_g = 0, chunk_n = 0;
  for (int ci = 0; ci < 4; ++ci) {
    int C = cand[ci];
    int CG = G_GRAPHS / C, CN = CG * N_NODES;
    char* p = (char*)d_ws;
    auto alloc = [&](size_t bytes) { char* r = p; p += (bytes + 255) & ~(size_t)255; return r; };
    half_t* t_h1    = (half_t*)alloc((size_t)CN * HC * 2);
    half_t* t_xlr2c = (half_t*)alloc((size_t)CN * 1024 * 2);
    half_t* t_h2    = (half_t*)alloc((size_t)G_GRAPHS * 2112 * 2);
    half_t* t_B2    = (half_t*)alloc((size_t)1024 * 512 * 2);
    half_t* t_W1f   = (half_t*)alloc((size_t)512 * 2112 * 2);
    float*  t_X1p   = (float*)alloc((size_t)4 * G_GRAPHS * 512 * 4);
    if ((size_t)(p - (char*)d_ws) <= ws_size) {
      nchunks = C; chunk_g = CG; chunk_n = CN;
      h1 = t_h1; xlr2c = t_xlr2c; h2 = t_h2; B2 = t_B2; W1f = t_W1f;
      X1p = t_X1p;
      break;
    }
  }
  if (nchunks == 0) return;   // guard: zero output instead of memory fault

  for (int c = 0; c < nchunks; ++c) {
    int g0 = c * chunk_g;
    int extra = (c == 0) ? CONV_BLOCKS : 0;
    gat1_kernel<<<chunk_g + extra, 512, 0, stream>>>(
        x, src, dst, eattr, g1_Wl, g1_Wr, g1_We, g1_att, g1_b, h1, g0, chunk_g,
        g2_Wl, g2_Wr, B2, l1_Wih, W1f);
    int R = chunk_n / 256;
    int gblocks = 8 * ((R + 7) / 8) * 4;
    gemm256_8p<<<gblocks, 512, 0, stream>>>(h1, B2, xlr2c, chunk_n);
    gat2_kernel<<<chunk_g, 512, 0, stream>>>(xlr2c, src, dst, eattr, g2_We,
                                             g2_att, g2_b, h2, g0);
  }

  // X1 partials = h2 @ l1_Wih^T (+biases in part 0), split-K=4, one dispatch
  {
    dim3 grid(192, 4);
    gemm_f16_splitk<<<grid, 256, 0, stream>>>(h2, W1f, X1p, l1_bih, l1_bhh,
                                              G_GRAPHS, 512);
  }

  // fused LSTM1 + x2 + LSTM2 + FC
  {
    size_t PS = (size_t)G_GRAPHS * 512;
    lstm_all<<<BATCH, 1024, 0, stream>>>(X1p, X1p + PS, X1p + 2 * PS, X1p + 3 * PS,
                                         l1_Whh, l2_Wih, l2_bih, l2_bhh, l2_Whh,
                                         fc_W, fc_b, out);
  }
}

// Round 3
// 346.788 us; speedup vs baseline: 1.0366x; 1.0212x over previous
//
#include <hip/hip_runtime.h>
#include <math.h>

// ---- problem constants ----
#define N_NODES 33
#define SEQ 24
#define BATCH 64
#define G_GRAPHS (BATCH * SEQ)          // 1536
#define EPG 64
#define E_EDGES (G_GRAPHS * EPG)        // 98304
#define N_TOTAL (G_GRAPHS * N_NODES)    // 50688
#define HID 64
#define HEADS 8
#define HC (HID * HEADS)                // 512
#define LSTM1_H 128
#define LSTM2_H 64
#define NEG_SLOPE 0.2f
// conv fused into gat1 chunk 0: 128 transpose tiles + 264 W1f blocks
#define CONV_BLOCKS (128 + 264)

__device__ __forceinline__ float sigmoidf_(float x) { return 1.f / (1.f + expf(-x)); }
__device__ __forceinline__ float eluf_(float x) { return x > 0.f ? x : expm1f(x); }
__device__ __forceinline__ float lreluf_(float x) { return x > 0.f ? x : NEG_SLOPE * x; }

typedef __attribute__((ext_vector_type(4))) float f32x4;
typedef _Float16 half_t;
typedef __attribute__((ext_vector_type(8))) _Float16 halfx8;

__device__ __forceinline__ void gl2lds16(const void* g, void* l) {
  __builtin_amdgcn_global_load_lds(
      (__attribute__((address_space(1))) const unsigned int*)g,
      (__attribute__((address_space(3))) unsigned int*)l, 16, 0, 0);
}

// ============================================================
// GAT layer 1, 512 threads (8 waves). Blocks >= gat_blocks do the one-time
// fp16 weight conversion: 128 LDS-transpose tiles + 264 elementwise W1f blocks.
// ============================================================
__global__ __launch_bounds__(512) void gat1_kernel(
    const float* __restrict__ x, const int* __restrict__ src, const int* __restrict__ dst,
    const float* __restrict__ ea, const float* __restrict__ Wl, const float* __restrict__ Wr,
    const float* __restrict__ We, const float* __restrict__ att, const float* __restrict__ bias,
    half_t* __restrict__ h1, int g0, int gat_blocks,
    const float* __restrict__ g2Wl, const float* __restrict__ g2Wr,
    half_t* __restrict__ B2, const float* __restrict__ W1, half_t* __restrict__ W1f) {
  const int tid = threadIdx.x;

  __shared__ alignas(16) float Wl_s[2 * 512];
  __shared__ alignas(16) float Wr_s[2 * 512];
  __shared__ alignas(16) float We_s[3 * 512];
  __shared__ alignas(16) float att_s[512];
  __shared__ float xs0_s[N_NODES + 1], xs1_s[N_NODES + 1];
  __shared__ float easX[EPG], easY[EPG], easZ[EPG];
  __shared__ float logit_s[HEADS * 65];
  __shared__ int sloc[EPG], dloc[EPG], deg[N_NODES], start[N_NODES], fill[N_NODES], elist[EPG];
  __shared__ float tr[64 * 65];          // transpose tile (conv path)

  if ((int)blockIdx.x >= gat_blocks) {
    int cb = blockIdx.x - gat_blocks;
    if (cb < 128) {
      // transpose B2[n][k] = [Wl|Wr][k][n], 64x64 tile, coalesced both ways
      int kt = cb & 7, nt = cb >> 3;
      int k0 = kt * 64, n0 = nt * 64;
      int r = tid >> 6, c = tid & 63;
      #pragma unroll
      for (int rr = 0; rr < 8; ++rr) {
        int kl = rr * 8 + r;
        int n = n0 + c;
        float v = (n < 512) ? g2Wl[(size_t)(k0 + kl) * 512 + n]
                            : g2Wr[(size_t)(k0 + kl) * 512 + n - 512];
        tr[kl * 65 + c] = v;
      }
      __syncthreads();
      #pragma unroll
      for (int rr = 0; rr < 8; ++rr) {
        int nl = rr * 8 + r;
        B2[(size_t)(n0 + nl) * 512 + k0 + c] = (half_t)tr[c * 65 + nl];
      }
    } else {
      int base = (cb - 128) * 4096 + tid;
      #pragma unroll
      for (int i = 0; i < 8; ++i) {
        int idx = base + i * 512;
        if (idx < 512 * 2112) W1f[idx] = (half_t)W1[idx];
      }
    }
    return;
  }

  const int g = g0 + blockIdx.x;
  const int nb = g * N_NODES, eb = g * EPG;
  const int lb = blockIdx.x * N_NODES;

  for (int i = tid; i < 1024; i += 512) { Wl_s[i] = Wl[i]; Wr_s[i] = Wr[i]; }
  for (int i = tid; i < 1536; i += 512) We_s[i] = We[i];
  if (tid < 512) att_s[tid] = att[tid];
  if (tid < 2 * N_NODES) {
    float v = x[nb * 2 + tid];
    if (tid & 1) xs1_s[tid >> 1] = v; else xs0_s[tid >> 1] = v;
  }
  if (tid < EPG) {
    easX[tid] = ea[(eb + tid) * 3 + 0];
    easY[tid] = ea[(eb + tid) * 3 + 1];
    easZ[tid] = ea[(eb + tid) * 3 + 2];
    sloc[tid] = src[eb + tid] - nb;
    dloc[tid] = dst[eb + tid] - nb;
  }
  if (tid < N_NODES) { deg[tid] = 0; fill[tid] = 0; }
  __syncthreads();
  if (tid < EPG) atomicAdd(&deg[dloc[tid]], 1);
  __syncthreads();
  if (tid == 0) { int a = 0; for (int n = 0; n < N_NODES; ++n) { start[n] = a; a += deg[n]; } }
  __syncthreads();
  if (tid < EPG) { int d = dloc[tid]; int p = atomicAdd(&fill[d], 1); elist[start[d] + p] = tid; }

  // logits: one pass, h = tid>>6 (wave-uniform), e = lane
  {
    int h = tid >> 6, e = tid & 63;
    int s = sloc[e], d = dloc[e];
    float xs0 = xs0_s[s], xs1 = xs1_s[s], xd0 = xs0_s[d], xd1 = xs1_s[d];
    float e0 = easX[e], e1 = easY[e], e2 = easZ[e];
    float acc = 0.f;
    int base = h * 64;
    #pragma unroll
    for (int c4 = 0; c4 < 16; ++c4) {
      int j = base + c4 * 4;
      f32x4 wl0 = *(const f32x4*)(Wl_s + j);
      f32x4 wl1 = *(const f32x4*)(Wl_s + 512 + j);
      f32x4 wr0 = *(const f32x4*)(Wr_s + j);
      f32x4 wr1 = *(const f32x4*)(Wr_s + 512 + j);
      f32x4 we0 = *(const f32x4*)(We_s + j);
      f32x4 we1 = *(const f32x4*)(We_s + 512 + j);
      f32x4 we2 = *(const f32x4*)(We_s + 1024 + j);
      f32x4 at  = *(const f32x4*)(att_s + j);
      #pragma unroll
      for (int q = 0; q < 4; ++q) {
        float v = xs0 * wl0[q] + xs1 * wl1[q]
                + xd0 * wr0[q] + xd1 * wr1[q]
                + e0 * we0[q] + e1 * we1[q] + e2 * we2[q];
        acc += lreluf_(v) * at[q];
      }
    }
    logit_s[h * 65 + e] = acc;
  }
  __syncthreads();

  // segment softmax: one pass, h = tid>>6, n = lane (skip n>=33)
  {
    int h = tid >> 6, n = tid & 63;
    if (n < N_NODES) {
      int s0 = start[n], dn = deg[n];
      float mx = -1e30f;
      for (int i = 0; i < dn; ++i) mx = fmaxf(mx, logit_s[h * 65 + elist[s0 + i]]);
      float den = 0.f;
      for (int i = 0; i < dn; ++i) den += expf(logit_s[h * 65 + elist[s0 + i]] - mx);
      float inv = 1.f / (den + 1e-16f);
      for (int i = 0; i < dn; ++i) {
        int e = elist[s0 + i];
        logit_s[h * 65 + e] = expf(logit_s[h * 65 + e] - mx) * inv;
      }
    }
  }
  __syncthreads();

  // aggregation: task = (n, 8-channel block); n = t>>6 wave-uniform, jb = lane
  for (int t = tid; t < N_NODES * 64; t += 512) {
    int n = t >> 6, jb = t & 63;
    int j0 = jb * 8, h = jb >> 3;
    f32x4 wa0 = *(const f32x4*)(Wl_s + j0);
    f32x4 wa1 = *(const f32x4*)(Wl_s + j0 + 4);
    f32x4 wb0 = *(const f32x4*)(Wl_s + 512 + j0);
    f32x4 wb1 = *(const f32x4*)(Wl_s + 512 + j0 + 4);
    float acc[8] = {};
    int s0 = start[n], dn = deg[n];
    for (int i = 0; i < dn; ++i) {
      int e = elist[s0 + i]; int s = sloc[e];
      float a = logit_s[h * 65 + e];
      float ax0 = a * xs0_s[s], ax1 = a * xs1_s[s];
      #pragma unroll
      for (int q = 0; q < 4; ++q) {
        acc[q]     += ax0 * wa0[q] + ax1 * wb0[q];
        acc[4 + q] += ax0 * wa1[q] + ax1 * wb1[q];
      }
    }
    f32x4 b0 = *(const f32x4*)(bias + j0);
    f32x4 b1 = *(const f32x4*)(bias + j0 + 4);
    halfx8 vh;
    #pragma unroll
    for (int cc = 0; cc < 8; ++cc) {
      float bb = (cc < 4) ? b0[cc] : b1[cc - 4];
      vh[cc] = (half_t)eluf_(acc[cc] + bb);
    }
    *(halfx8*)(h1 + (size_t)(lb + n) * HC + j0) = vh;
  }
}

// ============================================================
// Main GEMM, round-18: 128x256 tile, BK=64, 512 threads (8 waves, 2Mx4N).
// Changes vs round-17 (77us, MfmaUtil 27%):
//  * grid tail: 1584 tiles (6.19/CU, ~13% tail) vs 792 (3.09/CU, ~28%).
//    Bijective XCD swizzle, zero dead blocks.
//  * 2 fat phases per K-tile (16 MFMA each) -> 4 barriers/K-tile (was 8).
//  * all B-frags read in P1 and held in regs -> B-buffer of tile t is free
//    from t.P2 on, enabling counted vmcnt with only 2 stages (96 KiB):
//      t.P1: stage A(t+1); t.P2: stage B(t+2) into t's own B-buffer;
//      wait at t.P2 = vmcnt(4)  (drains B(t+1)+A(t+1), keeps B(t+2) flying)
//    Hazard ledger: every overwrite is >=1 barrier after lgkm-complete
//    reads; prologue = stage B0,A0,B1 -> vmcnt(4) -> bar.
//  * T2 8-slot XOR swizzle (verified 0 bank conflicts in round-17 with the
//    identical read macro), T5 setprio around MFMA clusters.
// A: M x 512 f16 row-major. B: 1024 x 512 f16 (row = out ch). C: M x 1024 f16.
// M must be divisible by 128.
// ============================================================
#define PHASE_BAR() do { asm volatile("" ::: "memory"); \
  __builtin_amdgcn_s_barrier(); asm volatile("" ::: "memory"); } while (0)

#define LDA8(S, rr, c) \
  (*(const halfx8*)((S) + (rr) * 64 + ((((c) ^ ((rr) & 7))) << 3)))

__global__ __launch_bounds__(512, 2) void gemm128x256(
    const half_t* __restrict__ A, const half_t* __restrict__ B,
    half_t* __restrict__ C, int M) {
  // A0 A1 (128x64 each = 8192 halfs), B0 B1 (256x64 each = 16384 halfs)
  __shared__ alignas(16) half_t lds[49152];   // 96 KiB

  const int R = M >> 7;
  const int nwg = R * 4;                // always % 8 == 0 here
  int bid = blockIdx.x;
  const int cpx = nwg >> 3;
  int swz = (bid & 7) * cpx + (bid >> 3);   // bijective XCD swizzle
  const int ct = swz & 3, r = swz >> 2;     // ct fast -> A-panel L2 reuse

  const int tid = threadIdx.x;
  const int wave = tid >> 6, lane = tid & 63;
  const int wm = wave >> 2, wn = wave & 3;  // 2M x 4N wave grid (64x64 each)
  const int bm = r << 7, bn = ct << 8;

  // staging swizzle: lane -> row (lane>>3) within 8-row group, source chunk
  const int rl = lane >> 3;
  const int gc = ((lane & 7) ^ rl) << 3;
  // fragment read: row fr, k-quarter kq
  const int fr = lane & 15;
  const int kq = lane >> 4;

  half_t* const Ab0 = lds;
  half_t* const Ab1 = lds + 8192;
  half_t* const Bb0 = lds + 16384;
  half_t* const Bb1 = lds + 32768;

  f32x4 acc[4][4];
  #pragma unroll
  for (int tm = 0; tm < 4; ++tm)
    #pragma unroll
    for (int tn = 0; tn < 4; ++tn) acc[tm][tn] = {0.f, 0.f, 0.f, 0.f};

  // stage all of A-tile kt (128 rows x 64): 2 gl2lds per wave
  auto stageA = [&](int kt) {
    half_t* Ls = (kt & 1) ? Ab1 : Ab0;
    #pragma unroll
    for (int i = 0; i < 2; ++i) {
      int r0 = i * 64 + wave * 8;
      gl2lds16(A + (size_t)(bm + r0 + rl) * 512 + kt * 64 + gc, Ls + r0 * 64);
    }
  };
  // stage all of B-tile kt (256 rows x 64): 4 gl2lds per wave
  auto stageB = [&](int kt) {
    half_t* Ls = (kt & 1) ? Bb1 : Bb0;
    #pragma unroll
    for (int i = 0; i < 4; ++i) {
      int r0 = i * 64 + wave * 8;
      gl2lds16(B + (size_t)(bn + r0 + rl) * 512 + kt * 64 + gc, Ls + r0 * 64);
    }
  };

  // ---- prologue: B0, A0 staged+drained; B1 left in flight ----
  stageB(0);
  stageA(0);
  stageB(1);
  asm volatile("s_waitcnt vmcnt(4)" ::: "memory");   // drain B0+A0 (oldest 6)
  PHASE_BAR();

  #pragma unroll
  for (int t = 0; t < 8; ++t) {
    const half_t* As = (t & 1) ? Ab1 : Ab0;
    const half_t* Bs = (t & 1) ? Bb1 : Bb0;
    halfx8 bf[4][2], afA[2][2], afB[2][2];

    // ---- P1: all B frags + A rows 0..31; stage A(t+1) ----
    #pragma unroll
    for (int tn = 0; tn < 4; ++tn)
      #pragma unroll
      for (int ks = 0; ks < 2; ++ks)
        bf[tn][ks] = LDA8(Bs, wn * 64 + tn * 16 + fr, ks * 4 + kq);
    #pragma unroll
    for (int tl = 0; tl < 2; ++tl)
      #pragma unroll
      for (int ks = 0; ks < 2; ++ks)
        afA[tl][ks] = LDA8(As, wm * 64 + tl * 16 + fr, ks * 4 + kq);
    if (t < 7) stageA(t + 1);
    PHASE_BAR();
    __builtin_amdgcn_s_setprio(1);
    #pragma unroll
    for (int ks = 0; ks < 2; ++ks)
      #pragma unroll
      for (int tl = 0; tl < 2; ++tl)
        #pragma unroll
        for (int tn = 0; tn < 4; ++tn)
          acc[tl][tn] = __builtin_amdgcn_mfma_f32_16x16x32_f16(
              afA[tl][ks], bf[tn][ks], acc[tl][tn], 0, 0, 0);
    __builtin_amdgcn_s_setprio(0);
    PHASE_BAR();

    // ---- P2: A rows 32..63; stage B(t+2) into t's own (freed) B-buffer ----
    #pragma unroll
    for (int tl = 0; tl < 2; ++tl)
      #pragma unroll
      for (int ks = 0; ks < 2; ++ks)
        afB[tl][ks] = LDA8(As, wm * 64 + (2 + tl) * 16 + fr, ks * 4 + kq);
    if (t < 6) {
      stageB(t + 2);
      asm volatile("s_waitcnt vmcnt(4)" ::: "memory");  // drain B(t+1)+A(t+1)
    } else if (t == 6) {
      asm volatile("s_waitcnt vmcnt(0)" ::: "memory");  // drain B(7)+A(7)
    }
    PHASE_BAR();
    __builtin_amdgcn_s_setprio(1);
    #pragma unroll
    for (int ks = 0; ks < 2; ++ks)
      #pragma unroll
      for (int tl = 0; tl < 2; ++tl)
        #pragma unroll
        for (int tn = 0; tn < 4; ++tn)
          acc[2 + tl][tn] = __builtin_amdgcn_mfma_f32_16x16x32_f16(
              afB[tl][ks], bf[tn][ks], acc[2 + tl][tn], 0, 0, 0);
    __builtin_amdgcn_s_setprio(0);
    PHASE_BAR();
  }

  // epilogue: fp16 bounce through LDS (whole 128x256 tile, stride 264),
  // then coalesced halfx8 stores. lds is free after the K-loop.
  half_t* Cs = lds;
  const int rq = (lane >> 4) * 4;
  const int cl0 = lane & 15;
  __syncthreads();
  #pragma unroll
  for (int tm = 0; tm < 4; ++tm)
    #pragma unroll
    for (int tn = 0; tn < 4; ++tn) {
      int cl = wn * 64 + tn * 16 + cl0;
      #pragma unroll
      for (int rr = 0; rr < 4; ++rr)
        Cs[(wm * 64 + tm * 16 + rq + rr) * 264 + cl] = (half_t)acc[tm][tn][rr];
    }
  __syncthreads();
  #pragma unroll
  for (int i = 0; i < 8; ++i) {
    int row = i * 16 + (tid >> 5);
    int col = (tid & 31) * 8;
    halfx8 v = *(const halfx8*)(Cs + row * 264 + col);
    *(halfx8*)(C + (size_t)(bm + row) * 1024 + bn + col) = v;
  }
}

// ============================================================
// final GEMM, split-K=4 in one dispatch (round-14 verified)
// ============================================================
__global__ __launch_bounds__(256) void gemm_f16_splitk(
    const half_t* __restrict__ A, const half_t* __restrict__ B,
    float* __restrict__ Cp, const float* __restrict__ bias1, const float* __restrict__ bias2,
    int M, int N) {
  constexpr int SA = 2112;
  __shared__ half_t lds[(64 + 64) * 64];
  half_t* A_s = lds;
  half_t* B_s = A_s + 2 * 64 * 32;

  const int part = blockIdx.y;
  const int koff = part ? 576 + (part - 1) * 512 : 0;
  const int kend = part ? 512 : 576;
  const half_t* Ap = A + koff;
  const half_t* Bp = B + koff;
  float* C = Cp + (size_t)part * M * N;

  const int R = M / 64, NT = N / 64;
  int b = blockIdx.x;
  int xcd = b & 7, q = b >> 3;
  int ct = q % NT, rg = q / NT;
  int r = rg * 8 + xcd;
  if (r >= R) return;

  const int tid = threadIdx.x;
  const int wave = tid >> 6, lane = tid & 63;
  const int wm = wave >> 1, wn = wave & 1;
  const int bm = r * 64, bn = ct * 64;

  const int rA = lane >> 2;
  const int swz = (rA & 3) ^ ((rA >> 2) & 3);
  const int cA = ((lane & 3) ^ swz) * 8;

  f32x4 acc[2][2];
  #pragma unroll
  for (int tm = 0; tm < 2; ++tm)
    #pragma unroll
    for (int tn = 0; tn < 2; ++tn) acc[tm][tn] = {0.f, 0.f, 0.f, 0.f};

  for (int k0 = 0; k0 < kend; k0 += 64) {
    #pragma unroll
    for (int p = 0; p < 2; ++p) {
      int kk = k0 + p * 32;
      int row = wave * 16;
      gl2lds16(Ap + (size_t)(bm + row + rA) * SA + kk + cA,
               A_s + p * 64 * 32 + row * 32);
      gl2lds16(Bp + (size_t)(bn + row + rA) * SA + kk + cA,
               B_s + p * 64 * 32 + row * 32);
    }
    __syncthreads();
    const int fr = lane & 15;
    const int fs = (fr & 3) ^ ((fr >> 2) & 3);
    const int fk = ((lane >> 4) ^ fs) * 8;
    #pragma unroll
    for (int p = 0; p < 2; ++p) {
      const int pA = p * 64 * 32, pB = p * 64 * 32;
      halfx8 af[2], bf[2];
      #pragma unroll
      for (int tm = 0; tm < 2; ++tm) {
        int rr = (wm * 2 + tm) * 16 + fr;
        af[tm] = *(const halfx8*)(A_s + pA + rr * 32 + fk);
      }
      #pragma unroll
      for (int tn = 0; tn < 2; ++tn) {
        int rr = (wn * 2 + tn) * 16 + fr;
        bf[tn] = *(const halfx8*)(B_s + pB + rr * 32 + fk);
      }
      #pragma unroll
      for (int tm = 0; tm < 2; ++tm)
        #pragma unroll
        for (int tn = 0; tn < 2; ++tn)
          acc[tm][tn] = __builtin_amdgcn_mfma_f32_16x16x32_f16(af[tm], bf[tn], acc[tm][tn], 0, 0, 0);
    }
    __syncthreads();
  }

  const int col0 = lane & 15, rq = (lane >> 4) * 4;
  #pragma unroll
  for (int tm = 0; tm < 2; ++tm)
    #pragma unroll
    for (int tn = 0; tn < 2; ++tn) {
      int col = bn + (wn * 2 + tn) * 16 + col0;
      float badd = (part == 0) ? (bias1[col] + bias2[col]) : 0.f;
      #pragma unroll
      for (int rr = 0; rr < 4; ++rr) {
        int row = bm + (wm * 2 + tm) * 16 + rq + rr;
        C[(size_t)row * N + col] = acc[tm][tn][rr] + badd;
      }
    }
}

// ============================================================
// GAT layer 2, 512 threads (8 waves)
// ============================================================
__global__ __launch_bounds__(512) void gat2_kernel(
    const half_t* __restrict__ xlr, const int* __restrict__ src, const int* __restrict__ dst,
    const float* __restrict__ ea, const float* __restrict__ We,
    const float* __restrict__ att, const float* __restrict__ bias,
    half_t* __restrict__ h2, int g0) {
  __shared__ alignas(16) float We_s[3 * 512];
  __shared__ alignas(16) float att_s[512];
  __shared__ float b_s[HID];
  __shared__ float easX[EPG], easY[EPG], easZ[EPG];
  __shared__ float logit_s[HEADS * 65];
  __shared__ int sloc[EPG], dloc[EPG], deg[N_NODES], start[N_NODES], fill[N_NODES], elist[EPG];

  const int g = g0 + blockIdx.x, tid = threadIdx.x;
  const int nb = g * N_NODES, eb = g * EPG;
  const int lb = blockIdx.x * N_NODES;
  const int wave = tid >> 6, lane = tid & 63;

  for (int i = tid; i < 1536; i += 512) We_s[i] = We[i];
  if (tid < 512) att_s[tid] = att[tid];
  if (tid < HID) b_s[tid] = bias[tid];
  if (tid < EPG) {
    easX[tid] = ea[(eb + tid) * 3 + 0];
    easY[tid] = ea[(eb + tid) * 3 + 1];
    easZ[tid] = ea[(eb + tid) * 3 + 2];
    sloc[tid] = src[eb + tid] - nb;
    dloc[tid] = dst[eb + tid] - nb;
  }
  if (tid < N_NODES) { deg[tid] = 0; fill[tid] = 0; }
  __syncthreads();
  if (tid < EPG) atomicAdd(&deg[dloc[tid]], 1);
  __syncthreads();
  if (tid == 0) { int a = 0; for (int n = 0; n < N_NODES; ++n) { start[n] = a; a += deg[n]; } }
  __syncthreads();
  if (tid < EPG) { int d = dloc[tid]; int p = atomicAdd(&fill[d], 1); elist[start[d] + p] = tid; }
  __syncthreads();

  const int j0 = lane * 8;
  float w0[8], w1[8], w2[8], at8[8];
  #pragma unroll
  for (int q = 0; q < 8; ++q) {
    w0[q] = We_s[j0 + q];
    w1[q] = We_s[512 + j0 + q];
    w2[q] = We_s[1024 + j0 + q];
    at8[q] = att_s[j0 + q];
  }

  // logits: one wave per edge (8 iterations at 8 waves)
  for (int e = wave; e < EPG; e += 8) {
    int s = sloc[e], d = dloc[e];
    halfx8 xlv = *((const halfx8*)(xlr + (size_t)(lb + s) * 1024) + lane);
    halfx8 xrv = *((const halfx8*)(xlr + (size_t)(lb + d) * 1024 + 512) + lane);
    float e0 = easX[e], e1 = easY[e], e2 = easZ[e];
    float acc = 0.f;
    #pragma unroll
    for (int q = 0; q < 8; ++q) {
      float v = (float)xlv[q] + (float)xrv[q] + e0 * w0[q] + e1 * w1[q] + e2 * w2[q];
      acc += lreluf_(v) * at8[q];
    }
    acc += __shfl_xor(acc, 1, 64);
    acc += __shfl_xor(acc, 2, 64);
    acc += __shfl_xor(acc, 4, 64);
    if ((lane & 7) == 0) logit_s[(lane >> 3) * 65 + e] = acc;
  }
  __syncthreads();

  // softmax: one pass, h = tid>>6, n = lane (skip n>=33)
  {
    int h = tid >> 6, n = tid & 63;
    if (n < N_NODES) {
      int s0 = start[n], dn = deg[n];
      float mx = -1e30f;
      for (int i = 0; i < dn; ++i) mx = fmaxf(mx, logit_s[h * 65 + elist[s0 + i]]);
      float den = 0.f;
      for (int i = 0; i < dn; ++i) den += expf(logit_s[h * 65 + elist[s0 + i]] - mx);
      float inv = 1.f / (den + 1e-16f);
      for (int i = 0; i < dn; ++i) {
        int e = elist[s0 + i];
        logit_s[h * 65 + e] = expf(logit_s[h * 65 + e] - mx) * inv;
      }
    }
  }
  __syncthreads();

  // aggregation: wave-task n (5 iterations at 8 waves), lane = HID channel
  for (int n = wave; n < N_NODES; n += 8) {
    float acc = 0.f;
    int s0 = start[n], dn = deg[n];
    for (int i = 0; i < dn; ++i) {
      int e = elist[s0 + i], s = sloc[e];
      const half_t* row = xlr + (size_t)(lb + s) * 1024 + lane;
      #pragma unroll
      for (int h = 0; h < 8; ++h)
        acc += logit_s[h * 65 + e] * (float)row[h * 64];
    }
    float v = eluf_(acc * 0.125f + b_s[lane]);
    h2[(size_t)(nb + n) * HID + lane] = (half_t)v;
  }
}

// ============================================================
// Fused LSTM1 + x2 + LSTM2 + FC (round-14 verified)
// ============================================================
__global__ __launch_bounds__(1024, 4) void lstm_all(
    const float* __restrict__ X0, const float* __restrict__ X1,
    const float* __restrict__ X2p, const float* __restrict__ X3,
    const float* __restrict__ Whh1,
    const float* __restrict__ Wih2, const float* __restrict__ bih2,
    const float* __restrict__ bhh2, const float* __restrict__ Whh2,
    const float* __restrict__ fcW, const float* __restrict__ fcb,
    float* __restrict__ out) {
  __shared__ float hs1[LSTM1_H], cs1[LSTM1_H], p1[512], gs1[512];
  __shared__ float Y1s[SEQ][LSTM1_H];
  __shared__ float hs2[LSTM2_H], cs2[LSTM2_H], p2[4 * 256], gs2[256];
  const int tid = threadIdx.x, b = blockIdx.x;
  const int j = tid & 511, half = tid >> 9;

  float4 w1[16];
  {
    const float4* wp = (const float4*)(Whh1 + (size_t)j * LSTM1_H + half * 64);
    #pragma unroll
    for (int q = 0; q < 16; ++q) w1[q] = wp[q];
  }
  if (tid < LSTM1_H) { hs1[tid] = 0.f; cs1[tid] = 0.f; }
  __syncthreads();
  for (int t = 0; t < SEQ; ++t) {
    const float* hb = hs1 + half * 64;
    float acc = 0.f;
    #pragma unroll
    for (int q = 0; q < 16; ++q) {
      acc += w1[q].x * hb[4 * q] + w1[q].y * hb[4 * q + 1]
           + w1[q].z * hb[4 * q + 2] + w1[q].w * hb[4 * q + 3];
    }
    if (half) p1[j] = acc;
    __syncthreads();
    if (!half) {
      size_t xo = ((size_t)b * SEQ + t) * 512 + j;
      gs1[j] = acc + p1[j] + X0[xo] + X1[xo] + X2p[xo] + X3[xo];
    }
    __syncthreads();
    if (tid < LSTM1_H) {
      float ig = sigmoidf_(gs1[tid]);
      float fg = sigmoidf_(gs1[LSTM1_H + tid]);
      float gg = tanhf(gs1[2 * LSTM1_H + tid]);
      float og = sigmoidf_(gs1[3 * LSTM1_H + tid]);
      float c = fg * cs1[tid] + ig * gg;
      cs1[tid] = c;
      float h = og * tanhf(c);
      hs1[tid] = h;
      Y1s[t][tid] = h;
    }
    __syncthreads();
  }

  const int j2 = tid & 255, qt = tid >> 8;
  float4 w2x[8], w2h[4];
  {
    const float4* wxp = (const float4*)(Wih2 + (size_t)j2 * LSTM1_H + qt * 32);
    #pragma unroll
    for (int q = 0; q < 8; ++q) w2x[q] = wxp[q];
    const float4* whp = (const float4*)(Whh2 + (size_t)j2 * LSTM2_H + qt * 16);
    #pragma unroll
    for (int q = 0; q < 4; ++q) w2h[q] = whp[q];
  }
  if (tid < LSTM2_H) { hs2[tid] = 0.f; cs2[tid] = 0.f; }
  __syncthreads();
  for (int t = 0; t < SEQ; ++t) {
    const float* y = Y1s[t] + qt * 32;
    const float* hb = hs2 + qt * 16;
    float acc = 0.f;
    #pragma unroll
    for (int q = 0; q < 8; ++q) {
      acc += w2x[q].x * y[4 * q] + w2x[q].y * y[4 * q + 1]
           + w2x[q].z * y[4 * q + 2] + w2x[q].w * y[4 * q + 3];
    }
    #pragma unroll
    for (int q = 0; q < 4; ++q) {
      acc += w2h[q].x * hb[4 * q] + w2h[q].y * hb[4 * q + 1]
           + w2h[q].z * hb[4 * q + 2] + w2h[q].w * hb[4 * q + 3];
    }
    p2[qt * 256 + j2] = acc;
    __syncthreads();
    if (qt == 0)
      gs2[j2] = p2[j2] + p2[256 + j2] + p2[512 + j2] + p2[768 + j2]
              + bih2[j2] + bhh2[j2];
    __syncthreads();
    if (tid < LSTM2_H) {
      float ig = sigmoidf_(gs2[tid]);
      float fg = sigmoidf_(gs2[LSTM2_H + tid]);
      float gg = tanhf(gs2[2 * LSTM2_H + tid]);
      float og = sigmoidf_(gs2[3 * LSTM2_H + tid]);
      float c = fg * cs2[tid] + ig * gg;
      cs2[tid] = c;
      hs2[tid] = og * tanhf(c);
    }
    __syncthreads();
  }
  if (tid < 4) {
    float acc = fcb[tid];
    #pragma unroll
    for (int k = 0; k < LSTM2_H; ++k) acc += fcW[tid * LSTM2_H + k] * hs2[k];
    out[b * 4 + tid] = acc;
  }
}

// ============================================================
extern "C" void kernel_launch(void* const* d_in, const int* in_sizes, int n_in,
                              void* d_out, int out_size, void* d_ws, size_t ws_size,
                              hipStream_t stream) {
  const float* x       = (const float*)d_in[0];
  const int*   eidx    = (const int*)d_in[1];
  const float* eattr   = (const float*)d_in[2];
  const float* g1_Wl   = (const float*)d_in[3];
  const float* g1_Wr   = (const float*)d_in[4];
  const float* g1_We   = (const float*)d_in[5];
  const float* g1_att  = (const float*)d_in[6];
  const float* g1_b    = (const float*)d_in[7];
  const float* g2_Wl   = (const float*)d_in[8];
  const float* g2_Wr   = (const float*)d_in[9];
  const float* g2_We   = (const float*)d_in[10];
  const float* g2_att  = (const float*)d_in[11];
  const float* g2_b    = (const float*)d_in[12];
  const float* l1_Wih  = (const float*)d_in[13];
  const float* l1_Whh  = (const float*)d_in[14];
  const float* l1_bih  = (const float*)d_in[15];
  const float* l1_bhh  = (const float*)d_in[16];
  const float* l2_Wih  = (const float*)d_in[17];
  const float* l2_Whh  = (const float*)d_in[18];
  const float* l2_bih  = (const float*)d_in[19];
  const float* l2_bhh  = (const float*)d_in[20];
  const float* fc_W    = (const float*)d_in[21];
  const float* fc_b    = (const float*)d_in[22];
  float* out = (float*)d_out;

  const int* src = eidx;
  const int* dst = eidx + E_EDGES;

  // ---- runtime-adaptive chunking (all chunk_n divisible by 128) ----
  const int cand[4] = {1, 2, 3, 6};
  int nchunks = 0;
  half_t *h1 = nullptr, *xlr2c = nullptr, *h2 = nullptr, *B2 = nullptr, *W1f = nullptr;
  float *X1p = nullptr;
  int chunk_g = 0, chunk_n = 0;
  for (int ci = 0; ci < 4; ++ci) {
    int C = cand[ci];
    int CG = G_GRAPHS / C, CN = CG * N_NODES;
    char* p = (char*)d_ws;
    auto alloc = [&](size_t bytes) { char* r = p; p += (bytes + 255) & ~(size_t)255; return r; };
    half_t* t_h1    = (half_t*)alloc((size_t)CN * HC * 2);
    half_t* t_xlr2c = (half_t*)alloc((size_t)CN * 1024 * 2);
    half_t* t_h2    = (half_t*)alloc((size_t)G_GRAPHS * 2112 * 2);
    half_t* t_B2    = (half_t*)alloc((size_t)1024 * 512 * 2);
    half_t* t_W1f   = (half_t*)alloc((size_t)512 * 2112 * 2);
    float*  t_X1p   = (float*)alloc((size_t)4 * G_GRAPHS * 512 * 4);
    if ((size_t)(p - (char*)d_ws) <= ws_size) {
      nchunks = C; chunk_g = CG; chunk_n = CN;
      h1 = t_h1; xlr2c = t_xlr2c; h2 = t_h2; B2 = t_B2; W1f = t_W1f;
      X1p = t_X1p;
      break;
    }
  }
  if (nchunks == 0) return;   // guard: zero output instead of memory fault

  for (int c = 0; c < nchunks; ++c) {
    int g0 = c * chunk_g;
    int extra = (c == 0) ? CONV_BLOCKS : 0;
    gat1_kernel<<<chunk_g + extra, 512, 0, stream>>>(
        x, src, dst, eattr, g1_Wl, g1_Wr, g1_We, g1_att, g1_b, h1, g0, chunk_g,
        g2_Wl, g2_Wr, B2, l1_Wih, W1f);
    int gblocks = (chunk_n / 128) * 4;    // %8 == 0 for all chunk candidates
    gemm128x256<<<gblocks, 512, 0, stream>>>(h1, B2, xlr2c, chunk_n);
    gat2_kernel<<<chunk_g, 512, 0, stream>>>(xlr2c, src, dst, eattr, g2_We,
                                             g2_att, g2_b, h2, g0);
  }

  // X1 partials = h2 @ l1_Wih^T (+biases in part 0), split-K=4, one dispatch
  {
    dim3 grid(192, 4);
    gemm_f16_splitk<<<grid, 256, 0, stream>>>(h2, W1f, X1p, l1_bih, l1_bhh,
                                              G_GRAPHS, 512);
  }

  // fused LSTM1 + x2 + LSTM2 + FC
  {
    size_t PS = (size_t)G_GRAPHS * 512;
    lstm_all<<<BATCH, 1024, 0, stream>>>(X1p, X1p + PS, X1p + 2 * PS, X1p + 3 * PS,
                                         l1_Whh, l2_Wih, l2_bih, l2_bhh, l2_Whh,
                                         fc_W, fc_b, out);
  }
}

// Round 4
// 340.869 us; speedup vs baseline: 1.0546x; 1.0174x over previous
//
#include <hip/hip_runtime.h>
#include <math.h>

// ---- problem constants ----
#define N_NODES 33
#define SEQ 24
#define BATCH 64
#define G_GRAPHS (BATCH * SEQ)          // 1536
#define EPG 64
#define E_EDGES (G_GRAPHS * EPG)        // 98304
#define N_TOTAL (G_GRAPHS * N_NODES)    // 50688
#define HID 64
#define HEADS 8
#define HC (HID * HEADS)                // 512
#define LSTM1_H 128
#define LSTM2_H 64
#define NEG_SLOPE 0.2f
// conv fused into gat1 chunk 0: 128 transpose tiles + 264 W1f blocks
#define CONV_BLOCKS (128 + 264)

__device__ __forceinline__ float sigmoidf_(float x) { return 1.f / (1.f + expf(-x)); }
__device__ __forceinline__ float eluf_(float x) { return x > 0.f ? x : expm1f(x); }
__device__ __forceinline__ float lreluf_(float x) { return x > 0.f ? x : NEG_SLOPE * x; }

typedef __attribute__((ext_vector_type(4))) float f32x4;
typedef _Float16 half_t;
typedef __attribute__((ext_vector_type(8))) _Float16 halfx8;

__device__ __forceinline__ void gl2lds16(const void* g, void* l) {
  __builtin_amdgcn_global_load_lds(
      (__attribute__((address_space(1))) const unsigned int*)g,
      (__attribute__((address_space(3))) unsigned int*)l, 16, 0, 0);
}

// ============================================================
// GAT layer 1, 512 threads (8 waves). Blocks >= gat_blocks do the one-time
// fp16 weight conversion: 128 LDS-transpose tiles + 264 elementwise W1f blocks.
// ============================================================
__global__ __launch_bounds__(512) void gat1_kernel(
    const float* __restrict__ x, const int* __restrict__ src, const int* __restrict__ dst,
    const float* __restrict__ ea, const float* __restrict__ Wl, const float* __restrict__ Wr,
    const float* __restrict__ We, const float* __restrict__ att, const float* __restrict__ bias,
    half_t* __restrict__ h1, int g0, int gat_blocks,
    const float* __restrict__ g2Wl, const float* __restrict__ g2Wr,
    half_t* __restrict__ B2, const float* __restrict__ W1, half_t* __restrict__ W1f) {
  const int tid = threadIdx.x;

  __shared__ alignas(16) float Wl_s[2 * 512];
  __shared__ alignas(16) float Wr_s[2 * 512];
  __shared__ alignas(16) float We_s[3 * 512];
  __shared__ alignas(16) float att_s[512];
  __shared__ float xs0_s[N_NODES + 1], xs1_s[N_NODES + 1];
  __shared__ float easX[EPG], easY[EPG], easZ[EPG];
  __shared__ float logit_s[HEADS * 65];
  __shared__ int sloc[EPG], dloc[EPG], deg[N_NODES], start[N_NODES], fill[N_NODES], elist[EPG];
  __shared__ float tr[64 * 65];          // transpose tile (conv path)

  if ((int)blockIdx.x >= gat_blocks) {
    int cb = blockIdx.x - gat_blocks;
    if (cb < 128) {
      // transpose B2[n][k] = [Wl|Wr][k][n], 64x64 tile, coalesced both ways
      int kt = cb & 7, nt = cb >> 3;
      int k0 = kt * 64, n0 = nt * 64;
      int r = tid >> 6, c = tid & 63;
      #pragma unroll
      for (int rr = 0; rr < 8; ++rr) {
        int kl = rr * 8 + r;
        int n = n0 + c;
        float v = (n < 512) ? g2Wl[(size_t)(k0 + kl) * 512 + n]
                            : g2Wr[(size_t)(k0 + kl) * 512 + n - 512];
        tr[kl * 65 + c] = v;
      }
      __syncthreads();
      #pragma unroll
      for (int rr = 0; rr < 8; ++rr) {
        int nl = rr * 8 + r;
        B2[(size_t)(n0 + nl) * 512 + k0 + c] = (half_t)tr[c * 65 + nl];
      }
    } else {
      int base = (cb - 128) * 4096 + tid;
      #pragma unroll
      for (int i = 0; i < 8; ++i) {
        int idx = base + i * 512;
        if (idx < 512 * 2112) W1f[idx] = (half_t)W1[idx];
      }
    }
    return;
  }

  const int g = g0 + blockIdx.x;
  const int nb = g * N_NODES, eb = g * EPG;
  const int lb = blockIdx.x * N_NODES;

  for (int i = tid; i < 1024; i += 512) { Wl_s[i] = Wl[i]; Wr_s[i] = Wr[i]; }
  for (int i = tid; i < 1536; i += 512) We_s[i] = We[i];
  if (tid < 512) att_s[tid] = att[tid];
  if (tid < 2 * N_NODES) {
    float v = x[nb * 2 + tid];
    if (tid & 1) xs1_s[tid >> 1] = v; else xs0_s[tid >> 1] = v;
  }
  if (tid < EPG) {
    easX[tid] = ea[(eb + tid) * 3 + 0];
    easY[tid] = ea[(eb + tid) * 3 + 1];
    easZ[tid] = ea[(eb + tid) * 3 + 2];
    sloc[tid] = src[eb + tid] - nb;
    dloc[tid] = dst[eb + tid] - nb;
  }
  if (tid < N_NODES) { deg[tid] = 0; fill[tid] = 0; }
  __syncthreads();
  if (tid < EPG) atomicAdd(&deg[dloc[tid]], 1);
  __syncthreads();
  if (tid == 0) { int a = 0; for (int n = 0; n < N_NODES; ++n) { start[n] = a; a += deg[n]; } }
  __syncthreads();
  if (tid < EPG) { int d = dloc[tid]; int p = atomicAdd(&fill[d], 1); elist[start[d] + p] = tid; }

  // logits: one pass, h = tid>>6 (wave-uniform), e = lane
  {
    int h = tid >> 6, e = tid & 63;
    int s = sloc[e], d = dloc[e];
    float xs0 = xs0_s[s], xs1 = xs1_s[s], xd0 = xs0_s[d], xd1 = xs1_s[d];
    float e0 = easX[e], e1 = easY[e], e2 = easZ[e];
    float acc = 0.f;
    int base = h * 64;
    #pragma unroll
    for (int c4 = 0; c4 < 16; ++c4) {
      int j = base + c4 * 4;
      f32x4 wl0 = *(const f32x4*)(Wl_s + j);
      f32x4 wl1 = *(const f32x4*)(Wl_s + 512 + j);
      f32x4 wr0 = *(const f32x4*)(Wr_s + j);
      f32x4 wr1 = *(const f32x4*)(Wr_s + 512 + j);
      f32x4 we0 = *(const f32x4*)(We_s + j);
      f32x4 we1 = *(const f32x4*)(We_s + 512 + j);
      f32x4 we2 = *(const f32x4*)(We_s + 1024 + j);
      f32x4 at  = *(const f32x4*)(att_s + j);
      #pragma unroll
      for (int q = 0; q < 4; ++q) {
        float v = xs0 * wl0[q] + xs1 * wl1[q]
                + xd0 * wr0[q] + xd1 * wr1[q]
                + e0 * we0[q] + e1 * we1[q] + e2 * we2[q];
        acc += lreluf_(v) * at[q];
      }
    }
    logit_s[h * 65 + e] = acc;
  }
  __syncthreads();

  // segment softmax: one pass, h = tid>>6, n = lane (skip n>=33)
  {
    int h = tid >> 6, n = tid & 63;
    if (n < N_NODES) {
      int s0 = start[n], dn = deg[n];
      float mx = -1e30f;
      for (int i = 0; i < dn; ++i) mx = fmaxf(mx, logit_s[h * 65 + elist[s0 + i]]);
      float den = 0.f;
      for (int i = 0; i < dn; ++i) den += expf(logit_s[h * 65 + elist[s0 + i]] - mx);
      float inv = 1.f / (den + 1e-16f);
      for (int i = 0; i < dn; ++i) {
        int e = elist[s0 + i];
        logit_s[h * 65 + e] = expf(logit_s[h * 65 + e] - mx) * inv;
      }
    }
  }
  __syncthreads();

  // aggregation: task = (n, 8-channel block); n = t>>6 wave-uniform, jb = lane
  for (int t = tid; t < N_NODES * 64; t += 512) {
    int n = t >> 6, jb = t & 63;
    int j0 = jb * 8, h = jb >> 3;
    f32x4 wa0 = *(const f32x4*)(Wl_s + j0);
    f32x4 wa1 = *(const f32x4*)(Wl_s + j0 + 4);
    f32x4 wb0 = *(const f32x4*)(Wl_s + 512 + j0);
    f32x4 wb1 = *(const f32x4*)(Wl_s + 512 + j0 + 4);
    float acc[8] = {};
    int s0 = start[n], dn = deg[n];
    for (int i = 0; i < dn; ++i) {
      int e = elist[s0 + i]; int s = sloc[e];
      float a = logit_s[h * 65 + e];
      float ax0 = a * xs0_s[s], ax1 = a * xs1_s[s];
      #pragma unroll
      for (int q = 0; q < 4; ++q) {
        acc[q]     += ax0 * wa0[q] + ax1 * wb0[q];
        acc[4 + q] += ax0 * wa1[q] + ax1 * wb1[q];
      }
    }
    f32x4 b0 = *(const f32x4*)(bias + j0);
    f32x4 b1 = *(const f32x4*)(bias + j0 + 4);
    halfx8 vh;
    #pragma unroll
    for (int cc = 0; cc < 8; ++cc) {
      float bb = (cc < 4) ? b0[cc] : b1[cc - 4];
      vh[cc] = (half_t)eluf_(acc[cc] + bb);
    }
    *(halfx8*)(h1 + (size_t)(lb + n) * HC + j0) = vh;
  }
}

// ============================================================
// Main GEMM, round-19: back to the m97 structure (128x128 tile, 256 threads,
// 4 waves 2x2, BK=64 single-stage, 2 barriers/K-step, 33.8 KB LDS ->
// 4 blocks/CU) but with the round-2/3 XOR-8 swizzle that measured exactly
// 0 bank conflicts (round-0 ancestor had 6.49M conflict cycles with the old
// 4-slot swizzle). Rationale: rounds 1-3 (96-128 KiB LDS = 1 block/CU,
// deep pipelines) all plateaued at MfmaUtil 24-28% — lockstep barriers with
// no co-resident block to cover stalls. m114: at >=3 blocks/CU the implicit
// cross-block overlap captures what explicit pipelining would add.
// Bijective XCD swizzle (nwg % 8 == 0 for all chunk sizes), ct-fast for
// A-panel L2 reuse. A: Mx512 f16. B: 1024x512 f16 (row-major by out-ch).
// C: Mx1024 f16. M % 128 == 0.
// ============================================================
#define LDA8(S, rr, c) \
  (*(const halfx8*)((S) + (rr) * 64 + ((((c) ^ ((rr) & 7))) << 3)))

__global__ __launch_bounds__(256, 4) void gemm_m97(
    const half_t* __restrict__ A, const half_t* __restrict__ B,
    half_t* __restrict__ C, int M) {
  // staging: A 128x64 + B 128x64 halfs = 32 KB; C-bounce 128x132 = 33 KB
  __shared__ alignas(16) half_t lds[128 * 132];

  half_t* const As = lds;                // 8192 halfs
  half_t* const Bs = lds + 8192;         // 8192 halfs

  const int R = M >> 7;                  // row tiles
  const int nwg = R * 8;                 // 8 col tiles; nwg % 8 == 0
  const int cpx = nwg >> 3;
  const int bid = blockIdx.x;
  const int swz = (bid & 7) * cpx + (bid >> 3);  // bijective XCD swizzle
  const int ct = swz & 7, r = swz >> 3;          // ct fast: A-panel L2 reuse

  const int tid = threadIdx.x;
  const int wave = tid >> 6, lane = tid & 63;
  const int wm = wave >> 1, wn = wave & 1;       // 2x2 waves, 64x64 each
  const int bm = r << 7, bn = ct << 7;

  // staging: lane -> row rl of 8-row group, pre-swizzled global chunk
  const int rl = lane >> 3;
  const int gc = ((lane & 7) ^ rl) << 3;
  // fragment read: row fr in 16-row tile, k-quarter kq
  const int fr = lane & 15;
  const int kq = lane >> 4;

  f32x4 acc[4][4];
  #pragma unroll
  for (int tm = 0; tm < 4; ++tm)
    #pragma unroll
    for (int tn = 0; tn < 4; ++tn) acc[tm][tn] = {0.f, 0.f, 0.f, 0.f};

  for (int t = 0; t < 8; ++t) {
    // stage K-tile t: A 128x64 + B 128x64, 8 gl2lds16 per wave
    #pragma unroll
    for (int i = 0; i < 4; ++i) {
      int r0 = i * 32 + wave * 8;
      gl2lds16(A + (size_t)(bm + r0 + rl) * 512 + t * 64 + gc, As + r0 * 64);
    }
    #pragma unroll
    for (int i = 0; i < 4; ++i) {
      int r0 = i * 32 + wave * 8;
      gl2lds16(B + (size_t)(bn + r0 + rl) * 512 + t * 64 + gc, Bs + r0 * 64);
    }
    __syncthreads();   // compiler drains vmcnt before barrier

    #pragma unroll
    for (int ks = 0; ks < 2; ++ks) {
      halfx8 af[4], bf[4];
      #pragma unroll
      for (int tm = 0; tm < 4; ++tm)
        af[tm] = LDA8(As, wm * 64 + tm * 16 + fr, ks * 4 + kq);
      #pragma unroll
      for (int tn = 0; tn < 4; ++tn)
        bf[tn] = LDA8(Bs, wn * 64 + tn * 16 + fr, ks * 4 + kq);
      #pragma unroll
      for (int tm = 0; tm < 4; ++tm)
        #pragma unroll
        for (int tn = 0; tn < 4; ++tn)
          acc[tm][tn] = __builtin_amdgcn_mfma_f32_16x16x32_f16(
              af[tm], bf[tn], acc[tm][tn], 0, 0, 0);
    }
    __syncthreads();   // protect LDS overwrite next K-step
  }

  // epilogue: fp16 bounce through LDS (stride 132), coalesced halfx8 stores
  half_t* Cs = lds;
  const int rq4 = (lane >> 4) * 4;
  const int cl0 = lane & 15;
  #pragma unroll
  for (int tm = 0; tm < 4; ++tm)
    #pragma unroll
    for (int tn = 0; tn < 4; ++tn) {
      int cl = wn * 64 + tn * 16 + cl0;
      #pragma unroll
      for (int rr = 0; rr < 4; ++rr)
        Cs[(wm * 64 + tm * 16 + rq4 + rr) * 132 + cl] = (half_t)acc[tm][tn][rr];
    }
  __syncthreads();
  #pragma unroll
  for (int pass = 0; pass < 8; ++pass) {
    int row = pass * 16 + (tid >> 4);
    int col = (tid & 15) * 8;
    halfx8 v = *(const halfx8*)(Cs + row * 132 + col);
    *(halfx8*)(C + (size_t)(bm + row) * 1024 + bn + col) = v;
  }
}

// ============================================================
// final GEMM, split-K=4 in one dispatch (round-14 verified)
// ============================================================
__global__ __launch_bounds__(256) void gemm_f16_splitk(
    const half_t* __restrict__ A, const half_t* __restrict__ B,
    float* __restrict__ Cp, const float* __restrict__ bias1, const float* __restrict__ bias2,
    int M, int N) {
  constexpr int SA = 2112;
  __shared__ half_t lds[(64 + 64) * 64];
  half_t* A_s = lds;
  half_t* B_s = A_s + 2 * 64 * 32;

  const int part = blockIdx.y;
  const int koff = part ? 576 + (part - 1) * 512 : 0;
  const int kend = part ? 512 : 576;
  const half_t* Ap = A + koff;
  const half_t* Bp = B + koff;
  float* C = Cp + (size_t)part * M * N;

  const int R = M / 64, NT = N / 64;
  int b = blockIdx.x;
  int xcd = b & 7, q = b >> 3;
  int ct = q % NT, rg = q / NT;
  int r = rg * 8 + xcd;
  if (r >= R) return;

  const int tid = threadIdx.x;
  const int wave = tid >> 6, lane = tid & 63;
  const int wm = wave >> 1, wn = wave & 1;
  const int bm = r * 64, bn = ct * 64;

  const int rA = lane >> 2;
  const int swz = (rA & 3) ^ ((rA >> 2) & 3);
  const int cA = ((lane & 3) ^ swz) * 8;

  f32x4 acc[2][2];
  #pragma unroll
  for (int tm = 0; tm < 2; ++tm)
    #pragma unroll
    for (int tn = 0; tn < 2; ++tn) acc[tm][tn] = {0.f, 0.f, 0.f, 0.f};

  for (int k0 = 0; k0 < kend; k0 += 64) {
    #pragma unroll
    for (int p = 0; p < 2; ++p) {
      int kk = k0 + p * 32;
      int row = wave * 16;
      gl2lds16(Ap + (size_t)(bm + row + rA) * SA + kk + cA,
               A_s + p * 64 * 32 + row * 32);
      gl2lds16(Bp + (size_t)(bn + row + rA) * SA + kk + cA,
               B_s + p * 64 * 32 + row * 32);
    }
    __syncthreads();
    const int fr = lane & 15;
    const int fs = (fr & 3) ^ ((fr >> 2) & 3);
    const int fk = ((lane >> 4) ^ fs) * 8;
    #pragma unroll
    for (int p = 0; p < 2; ++p) {
      const int pA = p * 64 * 32, pB = p * 64 * 32;
      halfx8 af[2], bf[2];
      #pragma unroll
      for (int tm = 0; tm < 2; ++tm) {
        int rr = (wm * 2 + tm) * 16 + fr;
        af[tm] = *(const halfx8*)(A_s + pA + rr * 32 + fk);
      }
      #pragma unroll
      for (int tn = 0; tn < 2; ++tn) {
        int rr = (wn * 2 + tn) * 16 + fr;
        bf[tn] = *(const halfx8*)(B_s + pB + rr * 32 + fk);
      }
      #pragma unroll
      for (int tm = 0; tm < 2; ++tm)
        #pragma unroll
        for (int tn = 0; tn < 2; ++tn)
          acc[tm][tn] = __builtin_amdgcn_mfma_f32_16x16x32_f16(af[tm], bf[tn], acc[tm][tn], 0, 0, 0);
    }
    __syncthreads();
  }

  const int col0 = lane & 15, rq = (lane >> 4) * 4;
  #pragma unroll
  for (int tm = 0; tm < 2; ++tm)
    #pragma unroll
    for (int tn = 0; tn < 2; ++tn) {
      int col = bn + (wn * 2 + tn) * 16 + col0;
      float badd = (part == 0) ? (bias1[col] + bias2[col]) : 0.f;
      #pragma unroll
      for (int rr = 0; rr < 4; ++rr) {
        int row = bm + (wm * 2 + tm) * 16 + rq + rr;
        C[(size_t)row * N + col] = acc[tm][tn][rr] + badd;
      }
    }
}

// ============================================================
// GAT layer 2, 512 threads (8 waves)
// ============================================================
__global__ __launch_bounds__(512) void gat2_kernel(
    const half_t* __restrict__ xlr, const int* __restrict__ src, const int* __restrict__ dst,
    const float* __restrict__ ea, const float* __restrict__ We,
    const float* __restrict__ att, const float* __restrict__ bias,
    half_t* __restrict__ h2, int g0) {
  __shared__ alignas(16) float We_s[3 * 512];
  __shared__ alignas(16) float att_s[512];
  __shared__ float b_s[HID];
  __shared__ float easX[EPG], easY[EPG], easZ[EPG];
  __shared__ float logit_s[HEADS * 65];
  __shared__ int sloc[EPG], dloc[EPG], deg[N_NODES], start[N_NODES], fill[N_NODES], elist[EPG];

  const int g = g0 + blockIdx.x, tid = threadIdx.x;
  const int nb = g * N_NODES, eb = g * EPG;
  const int lb = blockIdx.x * N_NODES;
  const int wave = tid >> 6, lane = tid & 63;

  for (int i = tid; i < 1536; i += 512) We_s[i] = We[i];
  if (tid < 512) att_s[tid] = att[tid];
  if (tid < HID) b_s[tid] = bias[tid];
  if (tid < EPG) {
    easX[tid] = ea[(eb + tid) * 3 + 0];
    easY[tid] = ea[(eb + tid) * 3 + 1];
    easZ[tid] = ea[(eb + tid) * 3 + 2];
    sloc[tid] = src[eb + tid] - nb;
    dloc[tid] = dst[eb + tid] - nb;
  }
  if (tid < N_NODES) { deg[tid] = 0; fill[tid] = 0; }
  __syncthreads();
  if (tid < EPG) atomicAdd(&deg[dloc[tid]], 1);
  __syncthreads();
  if (tid == 0) { int a = 0; for (int n = 0; n < N_NODES; ++n) { start[n] = a; a += deg[n]; } }
  __syncthreads();
  if (tid < EPG) { int d = dloc[tid]; int p = atomicAdd(&fill[d], 1); elist[start[d] + p] = tid; }
  __syncthreads();

  const int j0 = lane * 8;
  float w0[8], w1[8], w2[8], at8[8];
  #pragma unroll
  for (int q = 0; q < 8; ++q) {
    w0[q] = We_s[j0 + q];
    w1[q] = We_s[512 + j0 + q];
    w2[q] = We_s[1024 + j0 + q];
    at8[q] = att_s[j0 + q];
  }

  // logits: one wave per edge (8 iterations at 8 waves)
  for (int e = wave; e < EPG; e += 8) {
    int s = sloc[e], d = dloc[e];
    halfx8 xlv = *((const halfx8*)(xlr + (size_t)(lb + s) * 1024) + lane);
    halfx8 xrv = *((const halfx8*)(xlr + (size_t)(lb + d) * 1024 + 512) + lane);
    float e0 = easX[e], e1 = easY[e], e2 = easZ[e];
    float acc = 0.f;
    #pragma unroll
    for (int q = 0; q < 8; ++q) {
      float v = (float)xlv[q] + (float)xrv[q] + e0 * w0[q] + e1 * w1[q] + e2 * w2[q];
      acc += lreluf_(v) * at8[q];
    }
    acc += __shfl_xor(acc, 1, 64);
    acc += __shfl_xor(acc, 2, 64);
    acc += __shfl_xor(acc, 4, 64);
    if ((lane & 7) == 0) logit_s[(lane >> 3) * 65 + e] = acc;
  }
  __syncthreads();

  // softmax: one pass, h = tid>>6, n = lane (skip n>=33)
  {
    int h = tid >> 6, n = tid & 63;
    if (n < N_NODES) {
      int s0 = start[n], dn = deg[n];
      float mx = -1e30f;
      for (int i = 0; i < dn; ++i) mx = fmaxf(mx, logit_s[h * 65 + elist[s0 + i]]);
      float den = 0.f;
      for (int i = 0; i < dn; ++i) den += expf(logit_s[h * 65 + elist[s0 + i]] - mx);
      float inv = 1.f / (den + 1e-16f);
      for (int i = 0; i < dn; ++i) {
        int e = elist[s0 + i];
        logit_s[h * 65 + e] = expf(logit_s[h * 65 + e] - mx) * inv;
      }
    }
  }
  __syncthreads();

  // aggregation: wave-task n (5 iterations at 8 waves), lane = HID channel
  for (int n = wave; n < N_NODES; n += 8) {
    float acc = 0.f;
    int s0 = start[n], dn = deg[n];
    for (int i = 0; i < dn; ++i) {
      int e = elist[s0 + i], s = sloc[e];
      const half_t* row = xlr + (size_t)(lb + s) * 1024 + lane;
      #pragma unroll
      for (int h = 0; h < 8; ++h)
        acc += logit_s[h * 65 + e] * (float)row[h * 64];
    }
    float v = eluf_(acc * 0.125f + b_s[lane]);
    h2[(size_t)(nb + n) * HID + lane] = (half_t)v;
  }
}

// ============================================================
// Fused LSTM1 + x2 + LSTM2 + FC (round-14 verified)
// ============================================================
__global__ __launch_bounds__(1024, 4) void lstm_all(
    const float* __restrict__ X0, const float* __restrict__ X1,
    const float* __restrict__ X2p, const float* __restrict__ X3,
    const float* __restrict__ Whh1,
    const float* __restrict__ Wih2, const float* __restrict__ bih2,
    const float* __restrict__ bhh2, const float* __restrict__ Whh2,
    const float* __restrict__ fcW, const float* __restrict__ fcb,
    float* __restrict__ out) {
  __shared__ float hs1[LSTM1_H], cs1[LSTM1_H], p1[512], gs1[512];
  __shared__ float Y1s[SEQ][LSTM1_H];
  __shared__ float hs2[LSTM2_H], cs2[LSTM2_H], p2[4 * 256], gs2[256];
  const int tid = threadIdx.x, b = blockIdx.x;
  const int j = tid & 511, half = tid >> 9;

  float4 w1[16];
  {
    const float4* wp = (const float4*)(Whh1 + (size_t)j * LSTM1_H + half * 64);
    #pragma unroll
    for (int q = 0; q < 16; ++q) w1[q] = wp[q];
  }
  if (tid < LSTM1_H) { hs1[tid] = 0.f; cs1[tid] = 0.f; }
  __syncthreads();
  for (int t = 0; t < SEQ; ++t) {
    const float* hb = hs1 + half * 64;
    float acc = 0.f;
    #pragma unroll
    for (int q = 0; q < 16; ++q) {
      acc += w1[q].x * hb[4 * q] + w1[q].y * hb[4 * q + 1]
           + w1[q].z * hb[4 * q + 2] + w1[q].w * hb[4 * q + 3];
    }
    if (half) p1[j] = acc;
    __syncthreads();
    if (!half) {
      size_t xo = ((size_t)b * SEQ + t) * 512 + j;
      gs1[j] = acc + p1[j] + X0[xo] + X1[xo] + X2p[xo] + X3[xo];
    }
    __syncthreads();
    if (tid < LSTM1_H) {
      float ig = sigmoidf_(gs1[tid]);
      float fg = sigmoidf_(gs1[LSTM1_H + tid]);
      float gg = tanhf(gs1[2 * LSTM1_H + tid]);
      float og = sigmoidf_(gs1[3 * LSTM1_H + tid]);
      float c = fg * cs1[tid] + ig * gg;
      cs1[tid] = c;
      float h = og * tanhf(c);
      hs1[tid] = h;
      Y1s[t][tid] = h;
    }
    __syncthreads();
  }

  const int j2 = tid & 255, qt = tid >> 8;
  float4 w2x[8], w2h[4];
  {
    const float4* wxp = (const float4*)(Wih2 + (size_t)j2 * LSTM1_H + qt * 32);
    #pragma unroll
    for (int q = 0; q < 8; ++q) w2x[q] = wxp[q];
    const float4* whp = (const float4*)(Whh2 + (size_t)j2 * LSTM2_H + qt * 16);
    #pragma unroll
    for (int q = 0; q < 4; ++q) w2h[q] = whp[q];
  }
  if (tid < LSTM2_H) { hs2[tid] = 0.f; cs2[tid] = 0.f; }
  __syncthreads();
  for (int t = 0; t < SEQ; ++t) {
    const float* y = Y1s[t] + qt * 32;
    const float* hb = hs2 + qt * 16;
    float acc = 0.f;
    #pragma unroll
    for (int q = 0; q < 8; ++q) {
      acc += w2x[q].x * y[4 * q] + w2x[q].y * y[4 * q + 1]
           + w2x[q].z * y[4 * q + 2] + w2x[q].w * y[4 * q + 3];
    }
    #pragma unroll
    for (int q = 0; q < 4; ++q) {
      acc += w2h[q].x * hb[4 * q] + w2h[q].y * hb[4 * q + 1]
           + w2h[q].z * hb[4 * q + 2] + w2h[q].w * hb[4 * q + 3];
    }
    p2[qt * 256 + j2] = acc;
    __syncthreads();
    if (qt == 0)
      gs2[j2] = p2[j2] + p2[256 + j2] + p2[512 + j2] + p2[768 + j2]
              + bih2[j2] + bhh2[j2];
    __syncthreads();
    if (tid < LSTM2_H) {
      float ig = sigmoidf_(gs2[tid]);
      float fg = sigmoidf_(gs2[LSTM2_H + tid]);
      float gg = tanhf(gs2[2 * LSTM2_H + tid]);
      float og = sigmoidf_(gs2[3 * LSTM2_H + tid]);
      float c = fg * cs2[tid] + ig * gg;
      cs2[tid] = c;
      hs2[tid] = og * tanhf(c);
    }
    __syncthreads();
  }
  if (tid < 4) {
    float acc = fcb[tid];
    #pragma unroll
    for (int k = 0; k < LSTM2_H; ++k) acc += fcW[tid * LSTM2_H + k] * hs2[k];
    out[b * 4 + tid] = acc;
  }
}

// ============================================================
extern "C" void kernel_launch(void* const* d_in, const int* in_sizes, int n_in,
                              void* d_out, int out_size, void* d_ws, size_t ws_size,
                              hipStream_t stream) {
  const float* x       = (const float*)d_in[0];
  const int*   eidx    = (const int*)d_in[1];
  const float* eattr   = (const float*)d_in[2];
  const float* g1_Wl   = (const float*)d_in[3];
  const float* g1_Wr   = (const float*)d_in[4];
  const float* g1_We   = (const float*)d_in[5];
  const float* g1_att  = (const float*)d_in[6];
  const float* g1_b    = (const float*)d_in[7];
  const float* g2_Wl   = (const float*)d_in[8];
  const float* g2_Wr   = (const float*)d_in[9];
  const float* g2_We   = (const float*)d_in[10];
  const float* g2_att  = (const float*)d_in[11];
  const float* g2_b    = (const float*)d_in[12];
  const float* l1_Wih  = (const float*)d_in[13];
  const float* l1_Whh  = (const float*)d_in[14];
  const float* l1_bih  = (const float*)d_in[15];
  const float* l1_bhh  = (const float*)d_in[16];
  const float* l2_Wih  = (const float*)d_in[17];
  const float* l2_Whh  = (const float*)d_in[18];
  const float* l2_bih  = (const float*)d_in[19];
  const float* l2_bhh  = (const float*)d_in[20];
  const float* fc_W    = (const float*)d_in[21];
  const float* fc_b    = (const float*)d_in[22];
  float* out = (float*)d_out;

  const int* src = eidx;
  const int* dst = eidx + E_EDGES;

  // ---- runtime-adaptive chunking (all chunk_n divisible by 128) ----
  const int cand[4] = {1, 2, 3, 6};
  int nchunks = 0;
  half_t *h1 = nullptr, *xlr2c = nullptr, *h2 = nullptr, *B2 = nullptr, *W1f = nullptr;
  float *X1p = nullptr;
  int chunk_g = 0, chunk_n = 0;
  for (int ci = 0; ci < 4; ++ci) {
    int C = cand[ci];
    int CG = G_GRAPHS / C, CN = CG * N_NODES;
    char* p = (char*)d_ws;
    auto alloc = [&](size_t bytes) { char* r = p; p += (bytes + 255) & ~(size_t)255; return r; };
    half_t* t_h1    = (half_t*)alloc((size_t)CN * HC * 2);
    half_t* t_xlr2c = (half_t*)alloc((size_t)CN * 1024 * 2);
    half_t* t_h2    = (half_t*)alloc((size_t)G_GRAPHS * 2112 * 2);
    half_t* t_B2    = (half_t*)alloc((size_t)1024 * 512 * 2);
    half_t* t_W1f   = (half_t*)alloc((size_t)512 * 2112 * 2);
    float*  t_X1p   = (float*)alloc((size_t)4 * G_GRAPHS * 512 * 4);
    if ((size_t)(p - (char*)d_ws) <= ws_size) {
      nchunks = C; chunk_g = CG; chunk_n = CN;
      h1 = t_h1; xlr2c = t_xlr2c; h2 = t_h2; B2 = t_B2; W1f = t_W1f;
      X1p = t_X1p;
      break;
    }
  }
  if (nchunks == 0) return;   // guard: zero output instead of memory fault

  for (int c = 0; c < nchunks; ++c) {
    int g0 = c * chunk_g;
    int extra = (c == 0) ? CONV_BLOCKS : 0;
    gat1_kernel<<<chunk_g + extra, 512, 0, stream>>>(
        x, src, dst, eattr, g1_Wl, g1_Wr, g1_We, g1_att, g1_b, h1, g0, chunk_g,
        g2_Wl, g2_Wr, B2, l1_Wih, W1f);
    int gblocks = (chunk_n / 128) * 8;    // % 8 == 0 for all chunk candidates
    gemm_m97<<<gblocks, 256, 0, stream>>>(h1, B2, xlr2c, chunk_n);
    gat2_kernel<<<chunk_g, 512, 0, stream>>>(xlr2c, src, dst, eattr, g2_We,
                                             g2_att, g2_b, h2, g0);
  }

  // X1 partials = h2 @ l1_Wih^T (+biases in part 0), split-K=4, one dispatch
  {
    dim3 grid(192, 4);
    gemm_f16_splitk<<<grid, 256, 0, stream>>>(h2, W1f, X1p, l1_bih, l1_bhh,
                                              G_GRAPHS, 512);
  }

  // fused LSTM1 + x2 + LSTM2 + FC
  {
    size_t PS = (size_t)G_GRAPHS * 512;
    lstm_all<<<BATCH, 1024, 0, stream>>>(X1p, X1p + PS, X1p + 2 * PS, X1p + 3 * PS,
                                         l1_Whh, l2_Wih, l2_bih, l2_bhh, l2_Whh,
                                         fc_W, fc_b, out);
  }
}